// Round 2
// baseline (1681.016 us; speedup 1.0000x reference)
//
#include <hip/hip_runtime.h>

typedef __bf16 bf16;
typedef __bf16 bf16x8 __attribute__((ext_vector_type(8)));
typedef float f32x4 __attribute__((ext_vector_type(4)));

#define NN 384
#define CC 128

#define MFMA16(a,b,c) __builtin_amdgcn_mfma_f32_16x16x32_bf16(a,b,c,0,0,0)

// ---------------- workspace layout (bytes) ----------------
// x bf16            [147456][128]  : 37,748,736
// nb_bias fp32      [q][k][4]      :  2,359,296  @ 37748736
// qkvg pack bf16    (128 KiB)      @ 40108032   <- was 64 KiB: overlapped opk (round-1 bug)
// o pack bf16       (32 KiB)       @ 40239104
#define WS_NB   37748736
#define WS_QKVG 40108032
#define WS_OP   40239104

// ---------------- K0: pre-pack weights into MFMA B-fragment order ----------------
// B-frag (16x16x32): lane l holds B[k = (l>>4)*8 + j][n = l&15], j=0..7
__global__ __launch_bounds__(256) void pack_kernel(
    const float* __restrict__ qw, const float* __restrict__ kw,
    const float* __restrict__ vw, const float* __restrict__ gw,
    const float* __restrict__ ow, bf16* __restrict__ qkvg, bf16* __restrict__ op)
{
  int tid = blockIdx.x*256 + threadIdx.x;
  int lane = tid & 63, frag = tid >> 6;
  if (frag < 128) {                       // ((wm*4+h)*4+t)*2+f
    int f = frag & 1, t = (frag>>1)&3, h = (frag>>3)&3, wm = frag>>5;
    const float* W = wm==0?qw: (wm==1?kw: (wm==2?vw: gw));
    float sc = (wm==0) ? 0.17677669529663687f : 1.0f;   // q * D^-0.5 folded in
    int d = f*16 + (lane&15);
    #pragma unroll
    for (int j=0;j<8;j++){
      int c = t*32 + (lane>>4)*8 + j;
      qkvg[tid*8 + j] = (bf16)(W[c*128 + h*32 + d]*sc);
    }
  } else if (frag < 160) {                // o_w: frag = t(head)*8 + f(col frag)
    int fr = frag - 128, f = fr & 7, t = fr>>3;
    int c = f*16 + (lane&15);
    #pragma unroll
    for (int j=0;j<8;j++){
      int d = (lane>>4)*8 + j;
      op[(fr*64 + lane)*8 + j] = (bf16)ow[(t*32 + d)*128 + c];
    }
  }
}

// ---------------- K1: LayerNorm (fp32) -> x bf16, + nb_bias ----------------
__global__ __launch_bounds__(256) void ln_kernel(
    const float* __restrict__ pa, const float* __restrict__ lns,
    const float* __restrict__ lnb, const float* __restrict__ fw,
    bf16* __restrict__ xout, float* __restrict__ nbout)
{
  int wid = (blockIdx.x*256 + threadIdx.x) >> 6;
  int lane = threadIdx.x & 63;
  int nw = (gridDim.x*256) >> 6;
  float2 sc = *(const float2*)(lns + lane*2);
  float2 bi = *(const float2*)(lnb + lane*2);
  float4 f0 = *(const float4*)(fw + lane*8);      // fw[2l][0..3]
  float4 f1 = *(const float4*)(fw + lane*8 + 4);  // fw[2l+1][0..3]
  for (int row = wid; row < NN*NN; row += nw){
    float2 v = *(const float2*)(pa + row*128 + lane*2);
    float s = v.x + v.y;
    float sq = v.x*v.x + v.y*v.y;
    #pragma unroll
    for (int m=1;m<64;m<<=1){ s += __shfl_xor(s,m); sq += __shfl_xor(sq,m); }
    float mu = s*(1.f/128.f);
    float rstd = rsqrtf(sq*(1.f/128.f) - mu*mu + 1e-5f);
    float x0 = (v.x-mu)*rstd*sc.x + bi.x;
    float x1 = (v.y-mu)*rstd*sc.y + bi.y;
    unsigned short h0 = __builtin_bit_cast(unsigned short, (bf16)x0);
    unsigned short h1 = __builtin_bit_cast(unsigned short, (bf16)x1);
    *(unsigned int*)((char*)xout + row*256 + lane*4) = ((unsigned int)h1<<16)|h0;
    float4 t;
    t.x = x0*f0.x + x1*f1.x;
    t.y = x0*f0.y + x1*f1.y;
    t.z = x0*f0.z + x1*f1.z;
    t.w = x0*f0.w + x1*f1.w;
    #pragma unroll
    for (int m=1;m<64;m<<=1){
      t.x += __shfl_xor(t.x,m); t.y += __shfl_xor(t.y,m);
      t.z += __shfl_xor(t.z,m); t.w += __shfl_xor(t.w,m);
    }
    if (lane==0) *(float4*)(nbout + row*4) = t;
  }
}

// ---------------- K2: fused attention, one block per pair-row b ----------------
// LDS map (bytes):
#define LDSX 0        // x_b bf16 [384][128], row stride 256B, swz ^((row&7)<<4)
#define LDSK 98304    // K bf16 [384][32], row stride 64B,    swz ^(((key>>1)&7)<<4)
#define LDSV 122880   // V^T bf16 [32][384], row stride 768B, swz ^((d&7)<<4)
#define LDSM 147456   // mask bias fp32 [384]
#define LDSS 148992   // per-wave 1KiB scratch [16][32] bf16, swz ^(((r>>1)&7)<<4)
#define LDSTOT 157184

__global__ __launch_bounds__(512, 2) void attn_kernel(
    const bf16* __restrict__ xg, const int* __restrict__ mask,
    const float* __restrict__ nb, const bf16* __restrict__ qkvg,
    const bf16* __restrict__ opk, const float* __restrict__ gb,
    const float* __restrict__ ob, float* __restrict__ out)
{
  extern __shared__ char sm[];
  const int b = blockIdx.x;
  const int tid = threadIdx.x;
  const int lane = tid & 63, w = tid >> 6;
  const int g = lane >> 4, l15 = lane & 15;
  const f32x4 Z = {0.f,0.f,0.f,0.f};

  // ---- stage x_b into LDS (swizzled), build mask bias ----
  {
    const uint4* src = (const uint4*)(xg + (size_t)b*NN*CC);
    #pragma unroll
    for (int it=0; it<12; ++it){
      unsigned u = it*512 + tid;            // 16B unit index, 6144 total
      unsigned row = u >> 4;
      unsigned dst = (u*16) ^ ((row&7)<<4);
      *(uint4*)(sm + LDSX + dst) = src[u];
    }
    if (tid < NN)
      *(float*)(sm + LDSM + tid*4) = 1e9f*((float)mask[b*NN + tid] - 1.0f);
  }

  f32x4 outa[3][8];
  #pragma unroll
  for (int p=0;p<3;p++)
    #pragma unroll
    for (int nf=0;nf<8;nf++) outa[p][nf] = Z;

  const int rowbase = w*48;

  for (int h=0; h<4; ++h){
    __syncthreads();
    // ---- cooperative K/V projection for head h (48 rows per wave) ----
    {
      f32x4 ak[3][2], av[3][2];
      #pragma unroll
      for (int mf=0;mf<3;mf++){
        #pragma unroll
        for (int f=0;f<2;f++){ ak[mf][f]=Z; av[mf][f]=Z; }
      }
      #pragma unroll
      for (int t=0;t<4;t++){
        bf16x8 a[3];
        #pragma unroll
        for (int mf=0;mf<3;mf++){
          unsigned row = rowbase + mf*16 + l15;
          a[mf] = *(const bf16x8*)(sm + LDSX + ((row*256 + t*64 + g*16) ^ ((row&7)<<4)));
        }
        #pragma unroll
        for (int f=0;f<2;f++){
          bf16x8 bk = *(const bf16x8*)(qkvg + (((1*4+h)*4+t)*2+f)*512 + lane*8);
          bf16x8 bv = *(const bf16x8*)(qkvg + (((2*4+h)*4+t)*2+f)*512 + lane*8);
          #pragma unroll
          for (int mf=0;mf<3;mf++){
            ak[mf][f] = MFMA16(a[mf], bk, ak[mf][f]);
            av[mf][f] = MFMA16(a[mf], bv, av[mf][f]);
          }
        }
      }
      #pragma unroll
      for (int mf=0;mf<3;mf++){
        #pragma unroll
        for (int f=0;f<2;f++){
          int d = f*16 + l15;
          #pragma unroll
          for (int j=0;j<4;j++){
            int key = rowbase + mf*16 + g*4 + j;
            *(bf16*)(sm + LDSK + ((key*64 + d*2) ^ (((key>>1)&7)<<4))) = (bf16)ak[mf][f][j];
            *(bf16*)(sm + LDSV + ((d*768 + key*2) ^ ((d&7)<<4)))       = (bf16)av[mf][f][j];
          }
        }
      }
    }
    __syncthreads();

    const unsigned scb = LDSS + w*1024;
    #pragma unroll
    for (int p=0;p<3;p++){
      const int qb = rowbase + p*16;
      // ---- Q projection (16 rows x 32) ----
      f32x4 q0=Z, q1=Z;
      #pragma unroll
      for (int t=0;t<4;t++){
        unsigned row = qb + l15;
        bf16x8 a  = *(const bf16x8*)(sm + LDSX + ((row*256 + t*64 + g*16) ^ ((row&7)<<4)));
        bf16x8 b0 = *(const bf16x8*)(qkvg + (((0*4+h)*4+t)*2+0)*512 + lane*8);
        bf16x8 b1 = *(const bf16x8*)(qkvg + (((0*4+h)*4+t)*2+1)*512 + lane*8);
        q0 = MFMA16(a, b0, q0);
        q1 = MFMA16(a, b1, q1);
      }
      // bounce Q accum -> A-frag layout through scratch
      #pragma unroll
      for (int f=0;f<2;f++){
        f32x4 qq = f ? q1 : q0;
        #pragma unroll
        for (int j=0;j<4;j++){
          unsigned r = g*4 + j, cb = (f*16 + l15)*2;
          *(bf16*)(sm + scb + ((r*64 + cb) ^ (((r>>1)&7)<<4))) = (bf16)qq[j];
        }
      }
      bf16x8 aq = *(const bf16x8*)(sm + scb + ((l15*64 + g*16) ^ (((l15>>1)&7)<<4)));
      // ---- S = q @ k^T  (24 frags = 384 keys) ----
      f32x4 S[24];
      #pragma unroll
      for (int nf=0;nf<24;nf++){
        int key = nf*16 + l15;
        bf16x8 bk = *(const bf16x8*)(sm + LDSK + ((key*64 + g*16) ^ (((key>>1)&7)<<4)));
        S[nf] = MFMA16(aq, bk, Z);
      }
      // ---- + mask bias + nb_bias ----
      #pragma unroll
      for (int nf=0;nf<24;nf++){
        int key = nf*16 + l15;
        float mkb = *(const float*)(sm + LDSM + key*4);
        #pragma unroll
        for (int j=0;j<4;j++){
          int qi = qb + g*4 + j;
          S[nf][j] += mkb + nb[(qi*NN + key)*4 + h];
        }
      }
      // ---- softmax over 384 keys (fp32) ----
      float mx[4] = {-3e38f,-3e38f,-3e38f,-3e38f};
      #pragma unroll
      for (int nf=0;nf<24;nf++){
        #pragma unroll
        for (int j=0;j<4;j++) mx[j] = fmaxf(mx[j], S[nf][j]);
      }
      #pragma unroll
      for (int m=1;m<16;m<<=1){
        #pragma unroll
        for (int j=0;j<4;j++) mx[j] = fmaxf(mx[j], __shfl_xor(mx[j], m));
      }
      float sum[4] = {0.f,0.f,0.f,0.f};
      #pragma unroll
      for (int nf=0;nf<24;nf++){
        #pragma unroll
        for (int j=0;j<4;j++){
          float pv = __expf(S[nf][j] - mx[j]);
          S[nf][j] = pv;
          sum[j] += pv;
        }
      }
      #pragma unroll
      for (int m=1;m<16;m<<=1){
        #pragma unroll
        for (int j=0;j<4;j++) sum[j] += __shfl_xor(sum[j], m);
      }
      float rs[4];
      #pragma unroll
      for (int j=0;j<4;j++) rs[j] = 1.f/sum[j];
      // ---- O = P @ V (bounce P per 32-key chunk) ----
      f32x4 o0=Z, o1=Z;
      #pragma unroll
      for (int t=0;t<12;t++){
        #pragma unroll
        for (int ff=0; ff<2; ff++){
          int nf = 2*t + ff;
          #pragma unroll
          for (int j=0;j<4;j++){
            unsigned r = g*4 + j, cb = (ff*16 + l15)*2;
            *(bf16*)(sm + scb + ((r*64 + cb) ^ (((r>>1)&7)<<4))) = (bf16)S[nf][j];
          }
        }
        bf16x8 ap  = *(const bf16x8*)(sm + scb + ((l15*64 + g*16) ^ (((l15>>1)&7)<<4)));
        bf16x8 bv0 = *(const bf16x8*)(sm + LDSV + ((l15*768      + t*64 + g*16) ^ ((l15&7)<<4)));
        bf16x8 bv1 = *(const bf16x8*)(sm + LDSV + (((16+l15)*768 + t*64 + g*16) ^ ((l15&7)<<4)));
        o0 = MFMA16(ap, bv0, o0);
        o1 = MFMA16(ap, bv1, o1);
      }
      // ---- gate ----
      f32x4 g0=Z, g1=Z;
      #pragma unroll
      for (int t=0;t<4;t++){
        unsigned row = qb + l15;
        bf16x8 a  = *(const bf16x8*)(sm + LDSX + ((row*256 + t*64 + g*16) ^ ((row&7)<<4)));
        bf16x8 b0 = *(const bf16x8*)(qkvg + (((3*4+h)*4+t)*2+0)*512 + lane*8);
        bf16x8 b1 = *(const bf16x8*)(qkvg + (((3*4+h)*4+t)*2+1)*512 + lane*8);
        g0 = MFMA16(a, b0, g0);
        g1 = MFMA16(a, b1, g1);
      }
      // ---- wg = (O/s)*sigmoid(G+gb); bounce; accumulate out-projection ----
      #pragma unroll
      for (int f=0;f<2;f++){
        f32x4 ov = f ? o1 : o0, gv = f ? g1 : g0;
        int d = f*16 + l15;
        float gbv = gb[h*32 + d];
        #pragma unroll
        for (int j=0;j<4;j++){
          float gt = 1.f/(1.f + __expf(-(gv[j] + gbv)));
          float wg = ov[j]*rs[j]*gt;
          unsigned r = g*4 + j, cb = (unsigned)d*2;
          *(bf16*)(sm + scb + ((r*64 + cb) ^ (((r>>1)&7)<<4))) = (bf16)wg;
        }
      }
      bf16x8 awg = *(const bf16x8*)(sm + scb + ((l15*64 + g*16) ^ (((l15>>1)&7)<<4)));
      #pragma unroll
      for (int nf=0;nf<8;nf++){
        bf16x8 bo = *(const bf16x8*)(opk + ((h*8+nf)*64 + lane)*8);
        outa[p][nf] = MFMA16(awg, bo, outa[p][nf]);
      }
    } // p
  } // h

  // ---- epilogue: + o_b, store fp32 ----
  #pragma unroll
  for (int p=0;p<3;p++){
    int qb = rowbase + p*16;
    #pragma unroll
    for (int nf=0;nf<8;nf++){
      int c = nf*16 + l15;
      float obv = ob[c];
      #pragma unroll
      for (int j=0;j<4;j++){
        int qi = qb + g*4 + j;
        out[((size_t)b*NN + qi)*CC + c] = outa[p][nf][j] + obv;
      }
    }
  }
}

extern "C" void kernel_launch(void* const* d_in, const int* in_sizes, int n_in,
                              void* d_out, int out_size, void* d_ws, size_t ws_size,
                              hipStream_t stream)
{
  (void)in_sizes; (void)n_in; (void)out_size; (void)ws_size;
  const float* pa  = (const float*)d_in[0];
  const int*   msk = (const int*)d_in[1];
  const float* lns = (const float*)d_in[2];
  const float* lnb = (const float*)d_in[3];
  const float* fw  = (const float*)d_in[4];
  const float* qw  = (const float*)d_in[5];
  const float* kw  = (const float*)d_in[6];
  const float* vw  = (const float*)d_in[7];
  const float* gw  = (const float*)d_in[8];
  const float* gbv = (const float*)d_in[9];
  const float* ow  = (const float*)d_in[10];
  const float* ob  = (const float*)d_in[11];
  float* out = (float*)d_out;

  char* ws = (char*)d_ws;
  bf16*  xbuf  = (bf16*)(ws);
  float* nbbuf = (float*)(ws + WS_NB);
  bf16*  qkvg  = (bf16*)(ws + WS_QKVG);
  bf16*  opk   = (bf16*)(ws + WS_OP);

  hipFuncSetAttribute((const void*)attn_kernel,
                      hipFuncAttributeMaxDynamicSharedMemorySize, LDSTOT);

  pack_kernel<<<40, 256, 0, stream>>>(qw, kw, vw, gw, ow, qkvg, opk);
  ln_kernel<<<1152, 256, 0, stream>>>(pa, lns, lnb, fw, xbuf, nbbuf);
  attn_kernel<<<384, 512, LDSTOT, stream>>>(xbuf, msk, nbbuf, qkvg, opk, gbv, ob, out);
}

// Round 3
// 838.463 us; speedup vs baseline: 2.0049x; 2.0049x over previous
//
#include <hip/hip_runtime.h>

typedef __bf16 bf16;
typedef __bf16 bf16x8 __attribute__((ext_vector_type(8)));
typedef float f32x4 __attribute__((ext_vector_type(4)));

#define NN 384
#define CC 128

#define MFMA16(a,b,c) __builtin_amdgcn_mfma_f32_16x16x32_bf16(a,b,c,0,0,0)

// ---------------- workspace layout (bytes) ----------------
// x bf16            [147456][128]  : 37,748,736
// nb_bias fp32      [h][q][k]      :  2,359,296  @ 37748736   (layout changed r3: coalesced reads)
// qkvg pack bf16    (128 KiB)      @ 40108032
// o pack bf16       (32 KiB)       @ 40239104
#define WS_NB   37748736
#define WS_QKVG 40108032
#define WS_OP   40239104

// ---------------- K0: pre-pack weights into MFMA B-fragment order ----------------
// B-frag (16x16x32): lane l holds B[k = (l>>4)*8 + j][n = l&15], j=0..7
__global__ __launch_bounds__(256) void pack_kernel(
    const float* __restrict__ qw, const float* __restrict__ kw,
    const float* __restrict__ vw, const float* __restrict__ gw,
    const float* __restrict__ ow, bf16* __restrict__ qkvg, bf16* __restrict__ op)
{
  int tid = blockIdx.x*256 + threadIdx.x;
  int lane = tid & 63, frag = tid >> 6;
  if (frag < 128) {                       // ((wm*4+h)*4+t)*2+f
    int f = frag & 1, t = (frag>>1)&3, h = (frag>>3)&3, wm = frag>>5;
    const float* W = wm==0?qw: (wm==1?kw: (wm==2?vw: gw));
    float sc = (wm==0) ? 0.17677669529663687f : 1.0f;   // q * D^-0.5 folded in
    int d = f*16 + (lane&15);
    #pragma unroll
    for (int j=0;j<8;j++){
      int c = t*32 + (lane>>4)*8 + j;
      qkvg[tid*8 + j] = (bf16)(W[c*128 + h*32 + d]*sc);
    }
  } else if (frag < 160) {                // o_w: frag = t(head)*8 + f(col frag)
    int fr = frag - 128, f = fr & 7, t = fr>>3;
    int c = f*16 + (lane&15);
    #pragma unroll
    for (int j=0;j<8;j++){
      int d = (lane>>4)*8 + j;
      op[(fr*64 + lane)*8 + j] = (bf16)ow[(t*32 + d)*128 + c];
    }
  }
}

// ---------------- K1: LayerNorm (fp32) -> x bf16, + nb_bias [h][q][k] ----------------
__global__ __launch_bounds__(256) void ln_kernel(
    const float* __restrict__ pa, const float* __restrict__ lns,
    const float* __restrict__ lnb, const float* __restrict__ fw,
    bf16* __restrict__ xout, float* __restrict__ nbout)
{
  int wid = (blockIdx.x*256 + threadIdx.x) >> 6;
  int lane = threadIdx.x & 63;
  int nw = (gridDim.x*256) >> 6;
  float2 sc = *(const float2*)(lns + lane*2);
  float2 bi = *(const float2*)(lnb + lane*2);
  float4 f0 = *(const float4*)(fw + lane*8);      // fw[2l][0..3]
  float4 f1 = *(const float4*)(fw + lane*8 + 4);  // fw[2l+1][0..3]
  for (int row = wid; row < NN*NN; row += nw){
    float2 v = *(const float2*)(pa + row*128 + lane*2);
    float s = v.x + v.y;
    float sq = v.x*v.x + v.y*v.y;
    #pragma unroll
    for (int m=1;m<64;m<<=1){ s += __shfl_xor(s,m); sq += __shfl_xor(sq,m); }
    float mu = s*(1.f/128.f);
    float rstd = rsqrtf(sq*(1.f/128.f) - mu*mu + 1e-5f);
    float x0 = (v.x-mu)*rstd*sc.x + bi.x;
    float x1 = (v.y-mu)*rstd*sc.y + bi.y;
    unsigned short h0 = __builtin_bit_cast(unsigned short, (bf16)x0);
    unsigned short h1 = __builtin_bit_cast(unsigned short, (bf16)x1);
    *(unsigned int*)((char*)xout + row*256 + lane*4) = ((unsigned int)h1<<16)|h0;
    float4 t;
    t.x = x0*f0.x + x1*f1.x;
    t.y = x0*f0.y + x1*f1.y;
    t.z = x0*f0.z + x1*f1.z;
    t.w = x0*f0.w + x1*f1.w;
    #pragma unroll
    for (int m=1;m<64;m<<=1){
      t.x += __shfl_xor(t.x,m); t.y += __shfl_xor(t.y,m);
      t.z += __shfl_xor(t.z,m); t.w += __shfl_xor(t.w,m);
    }
    // all lanes hold the reduced sums; lanes 0..3 write one head-plane each
    float vsel = (lane==0)?t.x : (lane==1)?t.y : (lane==2)?t.z : t.w;
    if (lane < 4) nbout[(size_t)lane*(NN*NN) + row] = vsel;
  }
}

// ---------------- K2: fused attention, one block per pair-row b ----------------
// LDS map (bytes):
#define LDSX 0        // x_b bf16 [384][128], row stride 256B, swz ^((row&7)<<4)
#define LDSK 98304    // K bf16 [384][32], row stride 64B,    swz ^(((key>>1)&7)<<4)
#define LDSV 122880   // V^T bf16 [32][384], row stride 768B, swz ^((d&7)<<4)
#define LDSM 147456   // mask bias fp32 [384]
#define LDSS 148992   // per-wave 1KiB scratch [16][32] bf16, swz ^(((r>>1)&7)<<4)
#define LDSTOT 157184

__global__ __launch_bounds__(512, 2) void attn_kernel(
    const bf16* __restrict__ xg, const int* __restrict__ mask,
    const float* __restrict__ nb, const bf16* __restrict__ qkvg,
    const bf16* __restrict__ opk, const float* __restrict__ gb,
    const float* __restrict__ ob, float* __restrict__ out)
{
  extern __shared__ char sm[];
  const int b = blockIdx.x;
  const int tid = threadIdx.x;
  const int lane = tid & 63, w = tid >> 6;
  const int g = lane >> 4, l15 = lane & 15;
  const f32x4 Z = {0.f,0.f,0.f,0.f};

  // ---- stage x_b into LDS (swizzled), build mask bias ----
  {
    const uint4* src = (const uint4*)(xg + (size_t)b*NN*CC);
    #pragma unroll
    for (int it=0; it<12; ++it){
      unsigned u = it*512 + tid;            // 16B unit index, 6144 total
      unsigned row = u >> 4;
      unsigned dst = (u*16) ^ ((row&7)<<4);
      *(uint4*)(sm + LDSX + dst) = src[u];
    }
    if (tid < NN)
      *(float*)(sm + LDSM + tid*4) = 1e9f*((float)mask[b*NN + tid] - 1.0f);
  }

  f32x4 outa[3][8];
  #pragma unroll
  for (int p=0;p<3;p++)
    #pragma unroll
    for (int nf=0;nf<8;nf++) outa[p][nf] = Z;

  const int rowbase = w*48;

  for (int h=0; h<4; ++h){
    __syncthreads();
    // ---- cooperative K/V projection for head h (48 rows per wave) ----
    {
      f32x4 ak[3][2], av[3][2];
      #pragma unroll
      for (int mf=0;mf<3;mf++){
        #pragma unroll
        for (int f=0;f<2;f++){ ak[mf][f]=Z; av[mf][f]=Z; }
      }
      #pragma unroll
      for (int t=0;t<4;t++){
        bf16x8 a[3];
        #pragma unroll
        for (int mf=0;mf<3;mf++){
          unsigned row = rowbase + mf*16 + l15;
          a[mf] = *(const bf16x8*)(sm + LDSX + ((row*256 + t*64 + g*16) ^ ((row&7)<<4)));
        }
        #pragma unroll
        for (int f=0;f<2;f++){
          bf16x8 bk = *(const bf16x8*)(qkvg + (((1*4+h)*4+t)*2+f)*512 + lane*8);
          bf16x8 bv = *(const bf16x8*)(qkvg + (((2*4+h)*4+t)*2+f)*512 + lane*8);
          #pragma unroll
          for (int mf=0;mf<3;mf++){
            ak[mf][f] = MFMA16(a[mf], bk, ak[mf][f]);
            av[mf][f] = MFMA16(a[mf], bv, av[mf][f]);
          }
        }
      }
      #pragma unroll
      for (int mf=0;mf<3;mf++){
        #pragma unroll
        for (int f=0;f<2;f++){
          int d = f*16 + l15;
          #pragma unroll
          for (int j=0;j<4;j++){
            int key = rowbase + mf*16 + g*4 + j;
            *(bf16*)(sm + LDSK + ((key*64 + d*2) ^ (((key>>1)&7)<<4))) = (bf16)ak[mf][f][j];
            *(bf16*)(sm + LDSV + ((d*768 + key*2) ^ ((d&7)<<4)))       = (bf16)av[mf][f][j];
          }
        }
      }
    }
    __syncthreads();

    const unsigned scb = LDSS + w*1024;
    #pragma unroll
    for (int p=0;p<3;p++){
      const int qb = rowbase + p*16;
      // ---- Q projection (16 rows x 32) ----
      f32x4 q0=Z, q1=Z;
      #pragma unroll
      for (int t=0;t<4;t++){
        unsigned row = qb + l15;
        bf16x8 a  = *(const bf16x8*)(sm + LDSX + ((row*256 + t*64 + g*16) ^ ((row&7)<<4)));
        bf16x8 b0 = *(const bf16x8*)(qkvg + (((0*4+h)*4+t)*2+0)*512 + lane*8);
        bf16x8 b1 = *(const bf16x8*)(qkvg + (((0*4+h)*4+t)*2+1)*512 + lane*8);
        q0 = MFMA16(a, b0, q0);
        q1 = MFMA16(a, b1, q1);
      }
      // bounce Q accum -> A-frag layout through scratch
      #pragma unroll
      for (int f=0;f<2;f++){
        f32x4 qq = f ? q1 : q0;
        #pragma unroll
        for (int j=0;j<4;j++){
          unsigned r = g*4 + j, cb = (f*16 + l15)*2;
          *(bf16*)(sm + scb + ((r*64 + cb) ^ (((r>>1)&7)<<4))) = (bf16)qq[j];
        }
      }
      bf16x8 aq = *(const bf16x8*)(sm + scb + ((l15*64 + g*16) ^ (((l15>>1)&7)<<4)));

      // ---- online softmax + PV over two 192-key chunks ----
      float m_[4], sum_[4];
      #pragma unroll
      for (int j=0;j<4;j++){ m_[j] = -3e38f; sum_[j] = 0.f; }
      f32x4 o0=Z, o1=Z;

      #pragma unroll
      for (int c=0;c<2;c++){
        f32x4 S[12];
        #pragma unroll
        for (int nf=0;nf<12;nf++){
          int key = c*192 + nf*16 + l15;
          bf16x8 bk = *(const bf16x8*)(sm + LDSK + ((key*64 + g*16) ^ (((key>>1)&7)<<4)));
          S[nf] = MFMA16(aq, bk, Z);
        }
        // biases: mask (LDS) + nb ([h][q][k], coalesced 64B)
        const float* nbh = nb + (size_t)h*(NN*NN) + (size_t)(qb + g*4)*NN + c*192 + l15;
        #pragma unroll
        for (int nf=0;nf<12;nf++){
          int key = c*192 + nf*16 + l15;
          float mkb = *(const float*)(sm + LDSM + key*4);
          #pragma unroll
          for (int j=0;j<4;j++)
            S[nf][j] += mkb + nbh[j*NN + nf*16];
        }
        // chunk max
        float cm[4] = {-3e38f,-3e38f,-3e38f,-3e38f};
        #pragma unroll
        for (int nf=0;nf<12;nf++){
          #pragma unroll
          for (int j=0;j<4;j++) cm[j] = fmaxf(cm[j], S[nf][j]);
        }
        #pragma unroll
        for (int m=1;m<16;m<<=1){
          #pragma unroll
          for (int j=0;j<4;j++) cm[j] = fmaxf(cm[j], __shfl_xor(cm[j], m));
        }
        float sc_[4];
        #pragma unroll
        for (int j=0;j<4;j++){
          float mn = fmaxf(m_[j], cm[j]);
          sc_[j] = __expf(m_[j] - mn);
          m_[j] = mn;
        }
        // exp + partial sums
        float ps[4] = {0.f,0.f,0.f,0.f};
        #pragma unroll
        for (int nf=0;nf<12;nf++){
          #pragma unroll
          for (int j=0;j<4;j++){
            float pv = __expf(S[nf][j] - m_[j]);
            S[nf][j] = pv;
            ps[j] += pv;
          }
        }
        #pragma unroll
        for (int m=1;m<16;m<<=1){
          #pragma unroll
          for (int j=0;j<4;j++) ps[j] += __shfl_xor(ps[j], m);
        }
        #pragma unroll
        for (int j=0;j<4;j++){
          sum_[j] = sum_[j]*sc_[j] + ps[j];
          o0[j] *= sc_[j];
          o1[j] *= sc_[j];
        }
        // PV for this chunk (bounce P per 32-key step)
        #pragma unroll
        for (int t=0;t<6;t++){
          int tg = c*6 + t;
          #pragma unroll
          for (int ff=0; ff<2; ff++){
            int nf = 2*t + ff;
            #pragma unroll
            for (int j=0;j<4;j++){
              unsigned r = g*4 + j, cb = (ff*16 + l15)*2;
              *(bf16*)(sm + scb + ((r*64 + cb) ^ (((r>>1)&7)<<4))) = (bf16)S[nf][j];
            }
          }
          bf16x8 ap  = *(const bf16x8*)(sm + scb + ((l15*64 + g*16) ^ (((l15>>1)&7)<<4)));
          bf16x8 bv0 = *(const bf16x8*)(sm + LDSV + ((l15*768      + tg*64 + g*16) ^ ((l15&7)<<4)));
          bf16x8 bv1 = *(const bf16x8*)(sm + LDSV + (((16+l15)*768 + tg*64 + g*16) ^ ((l15&7)<<4)));
          o0 = MFMA16(ap, bv0, o0);
          o1 = MFMA16(ap, bv1, o1);
        }
      } // c

      float rs[4];
      #pragma unroll
      for (int j=0;j<4;j++) rs[j] = 1.f/sum_[j];

      // ---- gate ----
      f32x4 g0=Z, g1=Z;
      #pragma unroll
      for (int t=0;t<4;t++){
        unsigned row = qb + l15;
        bf16x8 a  = *(const bf16x8*)(sm + LDSX + ((row*256 + t*64 + g*16) ^ ((row&7)<<4)));
        bf16x8 b0 = *(const bf16x8*)(qkvg + (((3*4+h)*4+t)*2+0)*512 + lane*8);
        bf16x8 b1 = *(const bf16x8*)(qkvg + (((3*4+h)*4+t)*2+1)*512 + lane*8);
        g0 = MFMA16(a, b0, g0);
        g1 = MFMA16(a, b1, g1);
      }
      // ---- wg = (O/s)*sigmoid(G+gb); bounce; accumulate out-projection ----
      #pragma unroll
      for (int f=0;f<2;f++){
        f32x4 ov = f ? o1 : o0, gv = f ? g1 : g0;
        int d = f*16 + l15;
        float gbv = gb[h*32 + d];
        #pragma unroll
        for (int j=0;j<4;j++){
          float gt = 1.f/(1.f + __expf(-(gv[j] + gbv)));
          float wg = ov[j]*rs[j]*gt;
          unsigned r = g*4 + j, cb = (unsigned)d*2;
          *(bf16*)(sm + scb + ((r*64 + cb) ^ (((r>>1)&7)<<4))) = (bf16)wg;
        }
      }
      bf16x8 awg = *(const bf16x8*)(sm + scb + ((l15*64 + g*16) ^ (((l15>>1)&7)<<4)));
      #pragma unroll
      for (int nf=0;nf<8;nf++){
        bf16x8 bo = *(const bf16x8*)(opk + ((h*8+nf)*64 + lane)*8);
        outa[p][nf] = MFMA16(awg, bo, outa[p][nf]);
      }
    } // p
  } // h

  // ---- epilogue: + o_b, store fp32 ----
  #pragma unroll
  for (int p=0;p<3;p++){
    int qb = rowbase + p*16;
    #pragma unroll
    for (int nf=0;nf<8;nf++){
      int c = nf*16 + l15;
      float obv = ob[c];
      #pragma unroll
      for (int j=0;j<4;j++){
        int qi = qb + g*4 + j;
        out[((size_t)b*NN + qi)*CC + c] = outa[p][nf][j] + obv;
      }
    }
  }
}

extern "C" void kernel_launch(void* const* d_in, const int* in_sizes, int n_in,
                              void* d_out, int out_size, void* d_ws, size_t ws_size,
                              hipStream_t stream)
{
  (void)in_sizes; (void)n_in; (void)out_size; (void)ws_size;
  const float* pa  = (const float*)d_in[0];
  const int*   msk = (const int*)d_in[1];
  const float* lns = (const float*)d_in[2];
  const float* lnb = (const float*)d_in[3];
  const float* fw  = (const float*)d_in[4];
  const float* qw  = (const float*)d_in[5];
  const float* kw  = (const float*)d_in[6];
  const float* vw  = (const float*)d_in[7];
  const float* gw  = (const float*)d_in[8];
  const float* gbv = (const float*)d_in[9];
  const float* ow  = (const float*)d_in[10];
  const float* ob  = (const float*)d_in[11];
  float* out = (float*)d_out;

  char* ws = (char*)d_ws;
  bf16*  xbuf  = (bf16*)(ws);
  float* nbbuf = (float*)(ws + WS_NB);
  bf16*  qkvg  = (bf16*)(ws + WS_QKVG);
  bf16*  opk   = (bf16*)(ws + WS_OP);

  hipFuncSetAttribute((const void*)attn_kernel,
                      hipFuncAttributeMaxDynamicSharedMemorySize, LDSTOT);

  pack_kernel<<<40, 256, 0, stream>>>(qw, kw, vw, gw, ow, qkvg, opk);
  ln_kernel<<<1152, 256, 0, stream>>>(pa, lns, lnb, fw, xbuf, nbbuf);
  attn_kernel<<<384, 512, LDSTOT, stream>>>(xbuf, msk, nbbuf, qkvg, opk, gbv, ob, out);
}

// Round 4
// 764.968 us; speedup vs baseline: 2.1975x; 1.0961x over previous
//
#include <hip/hip_runtime.h>

typedef __bf16 bf16;
typedef __bf16 bf16x8 __attribute__((ext_vector_type(8)));
typedef float f32x4 __attribute__((ext_vector_type(4)));

#define NN 384
#define CC 128

#define MFMA16(a,b,c) __builtin_amdgcn_mfma_f32_16x16x32_bf16(a,b,c,0,0,0)

// ---------------- workspace layout (bytes) ----------------
// x bf16            [147456][128]  : 37,748,736
// nb_bias fp32      [h][q][k]      :  2,359,296  @ 37748736
// qkvg pack bf16    (128 KiB)      @ 40108032
// o pack bf16       (32 KiB)       @ 40239104
#define WS_NB   37748736
#define WS_QKVG 40108032
#define WS_OP   40239104

// ---------------- K0: pre-pack weights into MFMA B-fragment order ----------------
// B-frag (16x16x32): lane l holds B[k = (l>>4)*8 + j][n = l&15], j=0..7
__global__ __launch_bounds__(256) void pack_kernel(
    const float* __restrict__ qw, const float* __restrict__ kw,
    const float* __restrict__ vw, const float* __restrict__ gw,
    const float* __restrict__ ow, bf16* __restrict__ qkvg, bf16* __restrict__ op)
{
  int tid = blockIdx.x*256 + threadIdx.x;
  int lane = tid & 63, frag = tid >> 6;
  if (frag < 128) {                       // ((wm*4+h)*4+t)*2+f
    int f = frag & 1, t = (frag>>1)&3, h = (frag>>3)&3, wm = frag>>5;
    const float* W = wm==0?qw: (wm==1?kw: (wm==2?vw: gw));
    float sc = (wm==0) ? 0.17677669529663687f : 1.0f;   // q * D^-0.5 folded in
    int d = f*16 + (lane&15);
    #pragma unroll
    for (int j=0;j<8;j++){
      int c = t*32 + (lane>>4)*8 + j;
      qkvg[tid*8 + j] = (bf16)(W[c*128 + h*32 + d]*sc);
    }
  } else if (frag < 160) {                // o_w: frag = t(head)*8 + f(col frag)
    int fr = frag - 128, f = fr & 7, t = fr>>3;
    int c = f*16 + (lane&15);
    #pragma unroll
    for (int j=0;j<8;j++){
      int d = (lane>>4)*8 + j;
      op[(fr*64 + lane)*8 + j] = (bf16)ow[(t*32 + d)*128 + c];
    }
  }
}

// ---------------- K1: LayerNorm (fp32) -> x bf16, + nb_bias [h][q][k] ----------------
__global__ __launch_bounds__(256) void ln_kernel(
    const float* __restrict__ pa, const float* __restrict__ lns,
    const float* __restrict__ lnb, const float* __restrict__ fw,
    bf16* __restrict__ xout, float* __restrict__ nbout)
{
  int wid = (blockIdx.x*256 + threadIdx.x) >> 6;
  int lane = threadIdx.x & 63;
  int nw = (gridDim.x*256) >> 6;
  float2 sc = *(const float2*)(lns + lane*2);
  float2 bi = *(const float2*)(lnb + lane*2);
  float4 f0 = *(const float4*)(fw + lane*8);      // fw[2l][0..3]
  float4 f1 = *(const float4*)(fw + lane*8 + 4);  // fw[2l+1][0..3]
  for (int row = wid; row < NN*NN; row += nw){
    float2 v = *(const float2*)(pa + row*128 + lane*2);
    float s = v.x + v.y;
    float sq = v.x*v.x + v.y*v.y;
    #pragma unroll
    for (int m=1;m<64;m<<=1){ s += __shfl_xor(s,m); sq += __shfl_xor(sq,m); }
    float mu = s*(1.f/128.f);
    float rstd = rsqrtf(sq*(1.f/128.f) - mu*mu + 1e-5f);
    float x0 = (v.x-mu)*rstd*sc.x + bi.x;
    float x1 = (v.y-mu)*rstd*sc.y + bi.y;
    unsigned short h0 = __builtin_bit_cast(unsigned short, (bf16)x0);
    unsigned short h1 = __builtin_bit_cast(unsigned short, (bf16)x1);
    *(unsigned int*)((char*)xout + row*256 + lane*4) = ((unsigned int)h1<<16)|h0;
    float4 t;
    t.x = x0*f0.x + x1*f1.x;
    t.y = x0*f0.y + x1*f1.y;
    t.z = x0*f0.z + x1*f1.z;
    t.w = x0*f0.w + x1*f1.w;
    #pragma unroll
    for (int m=1;m<64;m<<=1){
      t.x += __shfl_xor(t.x,m); t.y += __shfl_xor(t.y,m);
      t.z += __shfl_xor(t.z,m); t.w += __shfl_xor(t.w,m);
    }
    // all lanes hold the reduced sums; lanes 0..3 write one head-plane each
    float vsel = (lane==0)?t.x : (lane==1)?t.y : (lane==2)?t.z : t.w;
    if (lane < 4) nbout[(size_t)lane*(NN*NN) + row] = vsel;
  }
}

// ---------------- K2: fused attention, one block per pair-row b ----------------
// r4: loop nest swapped to p-outer / h-inner so the out-projection accumulator
// is outa[8] (32 regs, per-p) instead of outa[3][8] (96 regs, whole-kernel).
// K/V projection recomputed per p (3x, cheap) -- removes the register spill
// that produced 245 MB of scratch traffic in r3.
// LDS map (bytes):
#define LDSX 0        // x_b bf16 [384][128], row stride 256B, swz ^((row&7)<<4)
#define LDSK 98304    // K bf16 [384][32], row stride 64B,    swz ^(((key>>1)&7)<<4)
#define LDSV 122880   // V^T bf16 [32][384], row stride 768B, swz ^((d&7)<<4)
#define LDSM 147456   // mask bias fp32 [384]
#define LDSS 148992   // per-wave 1KiB scratch [16][32] bf16, swz ^(((r>>1)&7)<<4)
#define LDSTOT 157184

__global__ __attribute__((amdgpu_flat_work_group_size(512,512), amdgpu_waves_per_eu(2,2)))
void attn_kernel(
    const bf16* __restrict__ xg, const int* __restrict__ mask,
    const float* __restrict__ nb, const bf16* __restrict__ qkvg,
    const bf16* __restrict__ opk, const float* __restrict__ gb,
    const float* __restrict__ ob, float* __restrict__ out)
{
  extern __shared__ char sm[];
  const int b = blockIdx.x;
  const int tid = threadIdx.x;
  const int lane = tid & 63, w = tid >> 6;
  const int g = lane >> 4, l15 = lane & 15;
  const f32x4 Z = {0.f,0.f,0.f,0.f};

  // ---- stage x_b into LDS (swizzled), build mask bias ----
  {
    const uint4* src = (const uint4*)(xg + (size_t)b*NN*CC);
    #pragma unroll
    for (int it=0; it<12; ++it){
      unsigned u = it*512 + tid;            // 16B unit index, 6144 total
      unsigned row = u >> 4;
      unsigned dst = (u*16) ^ ((row&7)<<4);
      *(uint4*)(sm + LDSX + dst) = src[u];
    }
    if (tid < NN)
      *(float*)(sm + LDSM + tid*4) = 1e9f*((float)mask[b*NN + tid] - 1.0f);
  }

  const int rowbase = w*48;

  for (int p=0;p<3;p++){
    const int qb = rowbase + p*16;
    f32x4 outa[8];
    #pragma unroll
    for (int nf=0;nf<8;nf++) outa[nf] = Z;

    for (int h=0; h<4; ++h){
      __syncthreads();   // prev iteration's K/V readers done (also covers X staging at p=0,h=0)
      // ---- cooperative K/V projection for head h (48 rows per wave) ----
      {
        f32x4 ak[3][2], av[3][2];
        #pragma unroll
        for (int mf=0;mf<3;mf++){
          #pragma unroll
          for (int f=0;f<2;f++){ ak[mf][f]=Z; av[mf][f]=Z; }
        }
        #pragma unroll
        for (int t=0;t<4;t++){
          bf16x8 a[3];
          #pragma unroll
          for (int mf=0;mf<3;mf++){
            unsigned row = rowbase + mf*16 + l15;
            a[mf] = *(const bf16x8*)(sm + LDSX + ((row*256 + t*64 + g*16) ^ ((row&7)<<4)));
          }
          #pragma unroll
          for (int f=0;f<2;f++){
            bf16x8 bk = *(const bf16x8*)(qkvg + (((1*4+h)*4+t)*2+f)*512 + lane*8);
            bf16x8 bv = *(const bf16x8*)(qkvg + (((2*4+h)*4+t)*2+f)*512 + lane*8);
            #pragma unroll
            for (int mf=0;mf<3;mf++){
              ak[mf][f] = MFMA16(a[mf], bk, ak[mf][f]);
              av[mf][f] = MFMA16(a[mf], bv, av[mf][f]);
            }
          }
        }
        #pragma unroll
        for (int mf=0;mf<3;mf++){
          #pragma unroll
          for (int f=0;f<2;f++){
            int d = f*16 + l15;
            #pragma unroll
            for (int j=0;j<4;j++){
              int key = rowbase + mf*16 + g*4 + j;
              *(bf16*)(sm + LDSK + ((key*64 + d*2) ^ (((key>>1)&7)<<4))) = (bf16)ak[mf][f][j];
              *(bf16*)(sm + LDSV + ((d*768 + key*2) ^ ((d&7)<<4)))       = (bf16)av[mf][f][j];
            }
          }
        }
      }
      __syncthreads();

      const unsigned scb = LDSS + w*1024;
      // ---- Q projection (16 rows x 32) ----
      f32x4 q0=Z, q1=Z;
      #pragma unroll
      for (int t=0;t<4;t++){
        unsigned row = qb + l15;
        bf16x8 a  = *(const bf16x8*)(sm + LDSX + ((row*256 + t*64 + g*16) ^ ((row&7)<<4)));
        bf16x8 b0 = *(const bf16x8*)(qkvg + (((0*4+h)*4+t)*2+0)*512 + lane*8);
        bf16x8 b1 = *(const bf16x8*)(qkvg + (((0*4+h)*4+t)*2+1)*512 + lane*8);
        q0 = MFMA16(a, b0, q0);
        q1 = MFMA16(a, b1, q1);
      }
      // bounce Q accum -> A-frag layout through scratch
      #pragma unroll
      for (int f=0;f<2;f++){
        f32x4 qq = f ? q1 : q0;
        #pragma unroll
        for (int j=0;j<4;j++){
          unsigned r = g*4 + j, cb = (f*16 + l15)*2;
          *(bf16*)(sm + scb + ((r*64 + cb) ^ (((r>>1)&7)<<4))) = (bf16)qq[j];
        }
      }
      bf16x8 aq = *(const bf16x8*)(sm + scb + ((l15*64 + g*16) ^ (((l15>>1)&7)<<4)));

      // ---- online softmax + PV over two 192-key chunks ----
      float m_[4], sum_[4];
      #pragma unroll
      for (int j=0;j<4;j++){ m_[j] = -3e38f; sum_[j] = 0.f; }
      f32x4 o0=Z, o1=Z;

      #pragma unroll
      for (int c=0;c<2;c++){
        f32x4 S[12];
        #pragma unroll
        for (int nf=0;nf<12;nf++){
          int key = c*192 + nf*16 + l15;
          bf16x8 bk = *(const bf16x8*)(sm + LDSK + ((key*64 + g*16) ^ (((key>>1)&7)<<4)));
          S[nf] = MFMA16(aq, bk, Z);
        }
        // biases: mask (LDS) + nb ([h][q][k], coalesced 64B)
        const float* nbh = nb + (size_t)h*(NN*NN) + (size_t)(qb + g*4)*NN + c*192 + l15;
        #pragma unroll
        for (int nf=0;nf<12;nf++){
          int key = c*192 + nf*16 + l15;
          float mkb = *(const float*)(sm + LDSM + key*4);
          #pragma unroll
          for (int j=0;j<4;j++)
            S[nf][j] += mkb + nbh[j*NN + nf*16];
        }
        // chunk max
        float cm[4] = {-3e38f,-3e38f,-3e38f,-3e38f};
        #pragma unroll
        for (int nf=0;nf<12;nf++){
          #pragma unroll
          for (int j=0;j<4;j++) cm[j] = fmaxf(cm[j], S[nf][j]);
        }
        #pragma unroll
        for (int m=1;m<16;m<<=1){
          #pragma unroll
          for (int j=0;j<4;j++) cm[j] = fmaxf(cm[j], __shfl_xor(cm[j], m));
        }
        float sc_[4];
        #pragma unroll
        for (int j=0;j<4;j++){
          float mn = fmaxf(m_[j], cm[j]);
          sc_[j] = __expf(m_[j] - mn);
          m_[j] = mn;
        }
        // exp + partial sums
        float ps[4] = {0.f,0.f,0.f,0.f};
        #pragma unroll
        for (int nf=0;nf<12;nf++){
          #pragma unroll
          for (int j=0;j<4;j++){
            float pv = __expf(S[nf][j] - m_[j]);
            S[nf][j] = pv;
            ps[j] += pv;
          }
        }
        #pragma unroll
        for (int m=1;m<16;m<<=1){
          #pragma unroll
          for (int j=0;j<4;j++) ps[j] += __shfl_xor(ps[j], m);
        }
        #pragma unroll
        for (int j=0;j<4;j++){
          sum_[j] = sum_[j]*sc_[j] + ps[j];
          o0[j] *= sc_[j];
          o1[j] *= sc_[j];
        }
        // PV for this chunk (bounce P per 32-key step)
        #pragma unroll
        for (int t=0;t<6;t++){
          int tg = c*6 + t;
          #pragma unroll
          for (int ff=0; ff<2; ff++){
            int nf = 2*t + ff;
            #pragma unroll
            for (int j=0;j<4;j++){
              unsigned r = g*4 + j, cb = (ff*16 + l15)*2;
              *(bf16*)(sm + scb + ((r*64 + cb) ^ (((r>>1)&7)<<4))) = (bf16)S[nf][j];
            }
          }
          bf16x8 ap  = *(const bf16x8*)(sm + scb + ((l15*64 + g*16) ^ (((l15>>1)&7)<<4)));
          bf16x8 bv0 = *(const bf16x8*)(sm + LDSV + ((l15*768      + tg*64 + g*16) ^ ((l15&7)<<4)));
          bf16x8 bv1 = *(const bf16x8*)(sm + LDSV + (((16+l15)*768 + tg*64 + g*16) ^ ((l15&7)<<4)));
          o0 = MFMA16(ap, bv0, o0);
          o1 = MFMA16(ap, bv1, o1);
        }
      } // c

      float rs[4];
      #pragma unroll
      for (int j=0;j<4;j++) rs[j] = 1.f/sum_[j];

      // ---- gate ----
      f32x4 g0=Z, g1=Z;
      #pragma unroll
      for (int t=0;t<4;t++){
        unsigned row = qb + l15;
        bf16x8 a  = *(const bf16x8*)(sm + LDSX + ((row*256 + t*64 + g*16) ^ ((row&7)<<4)));
        bf16x8 b0 = *(const bf16x8*)(qkvg + (((3*4+h)*4+t)*2+0)*512 + lane*8);
        bf16x8 b1 = *(const bf16x8*)(qkvg + (((3*4+h)*4+t)*2+1)*512 + lane*8);
        g0 = MFMA16(a, b0, g0);
        g1 = MFMA16(a, b1, g1);
      }
      // ---- wg = (O/s)*sigmoid(G+gb); bounce; accumulate out-projection ----
      #pragma unroll
      for (int f=0;f<2;f++){
        f32x4 ov = f ? o1 : o0, gv = f ? g1 : g0;
        int d = f*16 + l15;
        float gbv = gb[h*32 + d];
        #pragma unroll
        for (int j=0;j<4;j++){
          float gt = 1.f/(1.f + __expf(-(gv[j] + gbv)));
          float wg = ov[j]*rs[j]*gt;
          unsigned r = g*4 + j, cb = (unsigned)d*2;
          *(bf16*)(sm + scb + ((r*64 + cb) ^ (((r>>1)&7)<<4))) = (bf16)wg;
        }
      }
      bf16x8 awg = *(const bf16x8*)(sm + scb + ((l15*64 + g*16) ^ (((l15>>1)&7)<<4)));
      #pragma unroll
      for (int nf=0;nf<8;nf++){
        bf16x8 bo = *(const bf16x8*)(opk + ((h*8+nf)*64 + lane)*8);
        outa[nf] = MFMA16(awg, bo, outa[nf]);
      }
    } // h

    // ---- epilogue for this p: + o_b, store fp32 ----
    #pragma unroll
    for (int nf=0;nf<8;nf++){
      int c = nf*16 + l15;
      float obv = ob[c];
      #pragma unroll
      for (int j=0;j<4;j++){
        int qi = qb + g*4 + j;
        out[((size_t)b*NN + qi)*CC + c] = outa[nf][j] + obv;
      }
    }
  } // p
}

extern "C" void kernel_launch(void* const* d_in, const int* in_sizes, int n_in,
                              void* d_out, int out_size, void* d_ws, size_t ws_size,
                              hipStream_t stream)
{
  (void)in_sizes; (void)n_in; (void)out_size; (void)ws_size;
  const float* pa  = (const float*)d_in[0];
  const int*   msk = (const int*)d_in[1];
  const float* lns = (const float*)d_in[2];
  const float* lnb = (const float*)d_in[3];
  const float* fw  = (const float*)d_in[4];
  const float* qw  = (const float*)d_in[5];
  const float* kw  = (const float*)d_in[6];
  const float* vw  = (const float*)d_in[7];
  const float* gw  = (const float*)d_in[8];
  const float* gbv = (const float*)d_in[9];
  const float* ow  = (const float*)d_in[10];
  const float* ob  = (const float*)d_in[11];
  float* out = (float*)d_out;

  char* ws = (char*)d_ws;
  bf16*  xbuf  = (bf16*)(ws);
  float* nbbuf = (float*)(ws + WS_NB);
  bf16*  qkvg  = (bf16*)(ws + WS_QKVG);
  bf16*  opk   = (bf16*)(ws + WS_OP);

  hipFuncSetAttribute((const void*)attn_kernel,
                      hipFuncAttributeMaxDynamicSharedMemorySize, LDSTOT);

  pack_kernel<<<40, 256, 0, stream>>>(qw, kw, vw, gw, ow, qkvg, opk);
  ln_kernel<<<1152, 256, 0, stream>>>(pa, lns, lnb, fw, xbuf, nbbuf);
  attn_kernel<<<384, 512, LDSTOT, stream>>>(xbuf, msk, nbbuf, qkvg, opk, gbv, ob, out);
}

// Round 5
// 532.047 us; speedup vs baseline: 3.1595x; 1.4378x over previous
//
#include <hip/hip_runtime.h>

typedef __bf16 bf16;
typedef __bf16 bf16x8 __attribute__((ext_vector_type(8)));
typedef float f32x4 __attribute__((ext_vector_type(4)));
typedef unsigned int u32;

#define NN 384
#define CC 128

#define MFMA16(a,b,c) __builtin_amdgcn_mfma_f32_16x16x32_bf16(a,b,c,0,0,0)

// ---------------- workspace layout (bytes) ----------------
#define WS_NB   37748736          // nb fp32 [h][q][k]      2,359,296
#define WS_QKVG 40108032          // qkvg B-frag pack       131,072
#define WS_OP   40239104          // o_w pack               32,768
#define WS_KB   40271872          // K frags bf16 [b][h][24][64][8]  37,748,736
#define WS_VB   78020608          // V^T frags bf16 [b][h][24][...]  37,748,736
#define WS_NEED 115769344

__device__ __forceinline__ void async_copy16(void* lds_dst, const void* gsrc){
  __builtin_amdgcn_global_load_lds((const __attribute__((address_space(1))) u32*)gsrc,
                                   (__attribute__((address_space(3))) u32*)lds_dst, 16, 0, 0);
}

// ---------------- K0: pre-pack weights into MFMA B-fragment order ----------------
// B-frag (16x16x32): lane l holds B[k = (l>>4)*8 + j][n = l&15], j=0..7
__global__ __launch_bounds__(256) void pack_kernel(
    const float* __restrict__ qw, const float* __restrict__ kw,
    const float* __restrict__ vw, const float* __restrict__ gw,
    const float* __restrict__ ow, bf16* __restrict__ qkvg, bf16* __restrict__ op)
{
  int tid = blockIdx.x*256 + threadIdx.x;
  int lane = tid & 63, frag = tid >> 6;
  if (frag < 128) {                       // ((wm*4+h)*4+t)*2+f
    int f = frag & 1, t = (frag>>1)&3, h = (frag>>3)&3, wm = frag>>5;
    const float* W = wm==0?qw: (wm==1?kw: (wm==2?vw: gw));
    float sc = (wm==0) ? 0.17677669529663687f : 1.0f;   // q * D^-0.5 folded in
    int d = f*16 + (lane&15);
    #pragma unroll
    for (int j=0;j<8;j++){
      int c = t*32 + (lane>>4)*8 + j;
      qkvg[tid*8 + j] = (bf16)(W[c*128 + h*32 + d]*sc);
    }
  } else if (frag < 160) {                // o_w: frag = t(head)*8 + f(col frag)
    int fr = frag - 128, f = fr & 7, t = fr>>3;
    int c = f*16 + (lane&15);
    #pragma unroll
    for (int j=0;j<8;j++){
      int d = (lane>>4)*8 + j;
      op[(fr*64 + lane)*8 + j] = (bf16)ow[(t*32 + d)*128 + c];
    }
  }
}

// ---------------- K1: LayerNorm (fp32) -> x bf16, + nb_bias [h][q][k] ----------------
__global__ __launch_bounds__(256) void ln_kernel(
    const float* __restrict__ pa, const float* __restrict__ lns,
    const float* __restrict__ lnb, const float* __restrict__ fw,
    bf16* __restrict__ xout, float* __restrict__ nbout)
{
  int wid = (blockIdx.x*256 + threadIdx.x) >> 6;
  int lane = threadIdx.x & 63;
  int nw = (gridDim.x*256) >> 6;
  float2 sc = *(const float2*)(lns + lane*2);
  float2 bi = *(const float2*)(lnb + lane*2);
  float4 f0 = *(const float4*)(fw + lane*8);
  float4 f1 = *(const float4*)(fw + lane*8 + 4);
  for (int row = wid; row < NN*NN; row += nw){
    float2 v = *(const float2*)(pa + row*128 + lane*2);
    float s = v.x + v.y;
    float sq = v.x*v.x + v.y*v.y;
    #pragma unroll
    for (int m=1;m<64;m<<=1){ s += __shfl_xor(s,m); sq += __shfl_xor(sq,m); }
    float mu = s*(1.f/128.f);
    float rstd = rsqrtf(sq*(1.f/128.f) - mu*mu + 1e-5f);
    float x0 = (v.x-mu)*rstd*sc.x + bi.x;
    float x1 = (v.y-mu)*rstd*sc.y + bi.y;
    unsigned short h0 = __builtin_bit_cast(unsigned short, (bf16)x0);
    unsigned short h1 = __builtin_bit_cast(unsigned short, (bf16)x1);
    *(unsigned int*)((char*)xout + row*256 + lane*4) = ((unsigned int)h1<<16)|h0;
    float4 t;
    t.x = x0*f0.x + x1*f1.x;
    t.y = x0*f0.y + x1*f1.y;
    t.z = x0*f0.z + x1*f1.z;
    t.w = x0*f0.w + x1*f1.w;
    #pragma unroll
    for (int m=1;m<64;m<<=1){
      t.x += __shfl_xor(t.x,m); t.y += __shfl_xor(t.y,m);
      t.z += __shfl_xor(t.z,m); t.w += __shfl_xor(t.w,m);
    }
    float vsel = (lane==0)?t.x : (lane==1)?t.y : (lane==2)?t.z : t.w;
    if (lane < 4) nbout[(size_t)lane*(NN*NN) + row] = vsel;
  }
}

// ---------------- K2: K/V projection GEMM -> fragment-packed buffers ----------------
// wave W = blockIdx*4+w handles row-tile rt=W>>1, mat wm= 1(K) / 2(V).
// K frag per (b,h,tau):  lane holds K[key=l15][dim g*8+j]          (B-frag for S)
// V frag per (b,h,chunk,nf): lane holds V^T[key=(l>>4)*8+j][dim nf*16+l15] (B-frag for PV)
__global__ __launch_bounds__(256) void proj_kv_kernel(
    const bf16* __restrict__ xg, const bf16* __restrict__ qkvg,
    bf16* __restrict__ kbuf, bf16* __restrict__ vbuf)
{
  __shared__ char psm[16384];
  const int w = threadIdx.x>>6, lane = threadIdx.x&63, g = lane>>4, l15 = lane&15;
  const int W = blockIdx.x*4 + w;
  const int rt = W>>1, wm = 1 + (W&1);
  const f32x4 Z = {0.f,0.f,0.f,0.f};
  f32x4 acc[8];
  #pragma unroll
  for (int f8=0;f8<8;f8++) acc[f8] = Z;
  const bf16* xrow = xg + (size_t)(rt*16 + l15)*CC;
  #pragma unroll
  for (int t=0;t<4;t++){
    bf16x8 a = *(const bf16x8*)(xrow + t*32 + g*8);
    #pragma unroll
    for (int f8=0; f8<8; f8++){
      int h = f8>>1, fh = f8&1;
      bf16x8 bb = *(const bf16x8*)(qkvg + (((wm*4+h)*4+t)*2+fh)*512 + lane*8);
      acc[f8] = MFMA16(a, bb, acc[f8]);
    }
  }
  // bounce C/D accums -> scratch[16 rows][128 cols] bf16 (swizzled)
  char* scr = psm + w*4096;
  #pragma unroll
  for (int f8=0; f8<8; f8++){
    #pragma unroll
    for (int j=0;j<4;j++){
      unsigned r = g*4+j;
      *(bf16*)(scr + ((r*256 + (f8*16+l15)*2) ^ (((r>>1)&7)<<4))) = (bf16)acc[f8][j];
    }
  }
  const int bq = rt/24, tau = rt%24;
  if (wm==1){
    #pragma unroll
    for (int h=0;h<4;h++){
      bf16x8 kf = *(const bf16x8*)(scr + ((l15*256 + h*64 + g*16) ^ (((l15>>1)&7)<<4)));
      *(bf16x8*)(kbuf + (((size_t)(bq*4+h)*24 + tau)*64 + lane)*8) = kf;
    }
  } else {
    const int k0b = (lane>>5)*8 + (lane&1)*4;
    const int dl = (lane>>1)&15;
    #pragma unroll
    for (int h=0;h<4;h++){
      #pragma unroll
      for (int nf=0;nf<2;nf++){
        unsigned short tv[4];
        #pragma unroll
        for (int j2=0;j2<4;j2++){
          int k0 = k0b + j2;
          tv[j2] = *(unsigned short*)(scr + ((k0*256 + (h*32+nf*16+dl)*2) ^ (((k0>>1)&7)<<4)));
        }
        uint2 u;
        u.x = (u32)tv[0] | ((u32)tv[1]<<16);
        u.y = (u32)tv[2] | ((u32)tv[3]<<16);
        *(uint2*)((char*)vbuf + (((size_t)(bq*4+h)*24 + (tau&~1) + nf)*1024) + (tau&1)*512 + lane*8) = u;
      }
    }
  }
}

// ---------------- K3: fused attention v5 ----------------
#define LDSK5 0        // K frags: 24 x 1024 B
#define LDSV5 24576    // V frags: 24 x 1024 B
#define LDSM5 49152    // mask bias fp32 [384]
#define LDSS5 50688    // per-wave scratch 2 slots x 1 KiB
#define LDSTOT5 67072

__global__ __launch_bounds__(512, 4) void attn_kernel5(
    const bf16* __restrict__ xg, const int* __restrict__ mask,
    const float* __restrict__ nb, const bf16* __restrict__ qkvg,
    const bf16* __restrict__ kbuf, const bf16* __restrict__ vbuf,
    const bf16* __restrict__ opk, const float* __restrict__ gb,
    const float* __restrict__ ob, float* __restrict__ out)
{
  extern __shared__ char sm[];
  const int b = blockIdx.x;
  const int tid = threadIdx.x;
  const int lane = tid & 63, w = tid >> 6;
  const int g = lane >> 4, l15 = lane & 15;
  const f32x4 Z = {0.f,0.f,0.f,0.f};

  if (tid < NN)
    *(float*)(sm + LDSM5 + tid*4) = 1e9f*((float)mask[b*NN + tid] - 1.0f);

  const int rowbase = w*48;
  const size_t kvbase = (size_t)b*4*24576;   // bytes per (b): 4 heads x 24 KiB
  const unsigned scb = LDSS5 + w*2048;

  for (int p=0;p<3;p++){
    const int qb = rowbase + p*16;
    f32x4 outa[8];
    #pragma unroll
    for (int nf=0;nf<8;nf++) outa[nf] = Z;

    for (int h=0; h<4; ++h){
      __syncthreads();             // prior readers of LDS K/V done (covers mask at p0h0)
      {
        const char* kg = (const char*)kbuf + kvbase + (size_t)h*24576;
        const char* vg = (const char*)vbuf + kvbase + (size_t)h*24576;
        #pragma unroll
        for (int i=0;i<3;i++){
          unsigned u = (i*512 + w*64)*16;     // wave-uniform byte base
          async_copy16(sm + LDSK5 + u, kg + u + lane*16);
          async_copy16(sm + LDSV5 + u, vg + u + lane*16);
        }
      }
      __syncthreads();             // vmcnt(0) drain + all waves' stages visible

      // ---- Q projection (x A-frags direct from global) ----
      f32x4 q0=Z, q1=Z;
      #pragma unroll
      for (int t=0;t<4;t++){
        bf16x8 a  = *(const bf16x8*)(xg + (size_t)(b*NN + qb + l15)*CC + t*32 + g*8);
        bf16x8 b0 = *(const bf16x8*)(qkvg + (((0*4+h)*4+t)*2+0)*512 + lane*8);
        bf16x8 b1 = *(const bf16x8*)(qkvg + (((0*4+h)*4+t)*2+1)*512 + lane*8);
        q0 = MFMA16(a, b0, q0);
        q1 = MFMA16(a, b1, q1);
      }
      // bounce Q accum -> A-frag (slot 0)
      #pragma unroll
      for (int f=0;f<2;f++){
        f32x4 qq = f ? q1 : q0;
        #pragma unroll
        for (int j=0;j<4;j++){
          unsigned r = g*4 + j, cb = (f*16 + l15)*2;
          *(bf16*)(sm + scb + ((r*64 + cb) ^ (((r>>1)&7)<<4))) = (bf16)qq[j];
        }
      }
      bf16x8 aq = *(const bf16x8*)(sm + scb + ((l15*64 + g*16) ^ (((l15>>1)&7)<<4)));

      // ---- online softmax + PV over three 128-key chunks ----
      float m_[4], sum_[4];
      #pragma unroll
      for (int j=0;j<4;j++){ m_[j] = -3e38f; sum_[j] = 0.f; }
      f32x4 o0=Z, o1=Z;

      #pragma unroll
      for (int c=0;c<3;c++){
        f32x4 S[8];
        #pragma unroll
        for (int nf=0;nf<8;nf++){
          bf16x8 bk = *(const bf16x8*)(sm + LDSK5 + (c*8+nf)*1024 + lane*16);
          S[nf] = MFMA16(aq, bk, Z);
        }
        const float* nbh = nb + (size_t)h*(NN*NN) + (size_t)(qb + g*4)*NN + c*128 + l15;
        #pragma unroll
        for (int nf=0;nf<8;nf++){
          int key = c*128 + nf*16 + l15;
          float mkb = *(const float*)(sm + LDSM5 + key*4);
          #pragma unroll
          for (int j=0;j<4;j++)
            S[nf][j] += mkb + nbh[j*NN + nf*16];
        }
        float cm[4] = {-3e38f,-3e38f,-3e38f,-3e38f};
        #pragma unroll
        for (int nf=0;nf<8;nf++){
          #pragma unroll
          for (int j=0;j<4;j++) cm[j] = fmaxf(cm[j], S[nf][j]);
        }
        #pragma unroll
        for (int m=1;m<16;m<<=1){
          #pragma unroll
          for (int j=0;j<4;j++) cm[j] = fmaxf(cm[j], __shfl_xor(cm[j], m));
        }
        float sc_[4];
        #pragma unroll
        for (int j=0;j<4;j++){
          float mn = fmaxf(m_[j], cm[j]);
          sc_[j] = __expf(m_[j] - mn);
          m_[j] = mn;
        }
        float ps[4] = {0.f,0.f,0.f,0.f};
        #pragma unroll
        for (int nf=0;nf<8;nf++){
          #pragma unroll
          for (int j=0;j<4;j++){
            float pv = __expf(S[nf][j] - m_[j]);
            S[nf][j] = pv;
            ps[j] += pv;
          }
        }
        #pragma unroll
        for (int m=1;m<16;m<<=1){
          #pragma unroll
          for (int j=0;j<4;j++) ps[j] += __shfl_xor(ps[j], m);
        }
        #pragma unroll
        for (int j=0;j<4;j++){
          sum_[j] = sum_[j]*sc_[j] + ps[j];
          o0[j] *= sc_[j];
          o1[j] *= sc_[j];
        }
        // PV: 4 key-chunks of 32 (double-slot bounce)
        #pragma unroll
        for (int t=0;t<4;t++){
          int tg = c*4 + t;
          unsigned slot = scb + (t&1)*1024;
          #pragma unroll
          for (int ff=0; ff<2; ff++){
            int nf = 2*t + ff;
            #pragma unroll
            for (int j=0;j<4;j++){
              unsigned r = g*4 + j, cb2 = (ff*16 + l15)*2;
              *(bf16*)(sm + slot + ((r*64 + cb2) ^ (((r>>1)&7)<<4))) = (bf16)S[nf][j];
            }
          }
          bf16x8 ap  = *(const bf16x8*)(sm + slot + ((l15*64 + g*16) ^ (((l15>>1)&7)<<4)));
          bf16x8 bv0 = *(const bf16x8*)(sm + LDSV5 + (tg*2+0)*1024 + lane*16);
          bf16x8 bv1 = *(const bf16x8*)(sm + LDSV5 + (tg*2+1)*1024 + lane*16);
          o0 = MFMA16(ap, bv0, o0);
          o1 = MFMA16(ap, bv1, o1);
        }
      } // c

      float rs[4];
      #pragma unroll
      for (int j=0;j<4;j++) rs[j] = 1.f/sum_[j];

      // ---- gate (reload x frags) ----
      f32x4 g0=Z, g1=Z;
      #pragma unroll
      for (int t=0;t<4;t++){
        bf16x8 a  = *(const bf16x8*)(xg + (size_t)(b*NN + qb + l15)*CC + t*32 + g*8);
        bf16x8 b0 = *(const bf16x8*)(qkvg + (((3*4+h)*4+t)*2+0)*512 + lane*8);
        bf16x8 b1 = *(const bf16x8*)(qkvg + (((3*4+h)*4+t)*2+1)*512 + lane*8);
        g0 = MFMA16(a, b0, g0);
        g1 = MFMA16(a, b1, g1);
      }
      // ---- wg = (O/s)*sigmoid(G+gb); bounce (slot 0); out-projection ----
      #pragma unroll
      for (int f=0;f<2;f++){
        f32x4 ov = f ? o1 : o0, gv = f ? g1 : g0;
        int d = f*16 + l15;
        float gbv = gb[h*32 + d];
        #pragma unroll
        for (int j=0;j<4;j++){
          float gt = 1.f/(1.f + __expf(-(gv[j] + gbv)));
          float wg = ov[j]*rs[j]*gt;
          unsigned r = g*4 + j, cb2 = (unsigned)d*2;
          *(bf16*)(sm + scb + ((r*64 + cb2) ^ (((r>>1)&7)<<4))) = (bf16)wg;
        }
      }
      bf16x8 awg = *(const bf16x8*)(sm + scb + ((l15*64 + g*16) ^ (((l15>>1)&7)<<4)));
      #pragma unroll
      for (int nf=0;nf<8;nf++){
        bf16x8 bo = *(const bf16x8*)(opk + ((h*8+nf)*64 + lane)*8);
        outa[nf] = MFMA16(awg, bo, outa[nf]);
      }
    } // h

    #pragma unroll
    for (int nf=0;nf<8;nf++){
      int c = nf*16 + l15;
      float obv = ob[c];
      #pragma unroll
      for (int j=0;j<4;j++){
        int qi = qb + g*4 + j;
        out[((size_t)b*NN + qi)*CC + c] = outa[nf][j] + obv;
      }
    }
  } // p
}

// ---------------- Fallback: r4 attention (used if ws too small) ----------------
#define FLDSX 0
#define FLDSK 98304
#define FLDSV 122880
#define FLDSM 147456
#define FLDSS 148992
#define FLDSTOT 157184

__global__ __attribute__((amdgpu_flat_work_group_size(512,512), amdgpu_waves_per_eu(2,2)))
void attn_kernel_fb(
    const bf16* __restrict__ xg, const int* __restrict__ mask,
    const float* __restrict__ nb, const bf16* __restrict__ qkvg,
    const bf16* __restrict__ opk, const float* __restrict__ gb,
    const float* __restrict__ ob, float* __restrict__ out)
{
  extern __shared__ char sm[];
  const int b = blockIdx.x;
  const int tid = threadIdx.x;
  const int lane = tid & 63, w = tid >> 6;
  const int g = lane >> 4, l15 = lane & 15;
  const f32x4 Z = {0.f,0.f,0.f,0.f};
  {
    const uint4* src = (const uint4*)(xg + (size_t)b*NN*CC);
    #pragma unroll
    for (int it=0; it<12; ++it){
      unsigned u = it*512 + tid;
      unsigned row = u >> 4;
      unsigned dst = (u*16) ^ ((row&7)<<4);
      *(uint4*)(sm + FLDSX + dst) = src[u];
    }
    if (tid < NN)
      *(float*)(sm + FLDSM + tid*4) = 1e9f*((float)mask[b*NN + tid] - 1.0f);
  }
  const int rowbase = w*48;
  for (int p=0;p<3;p++){
    const int qb = rowbase + p*16;
    f32x4 outa[8];
    #pragma unroll
    for (int nf=0;nf<8;nf++) outa[nf] = Z;
    for (int h=0; h<4; ++h){
      __syncthreads();
      {
        f32x4 ak[3][2], av[3][2];
        #pragma unroll
        for (int mf=0;mf<3;mf++){
          #pragma unroll
          for (int f=0;f<2;f++){ ak[mf][f]=Z; av[mf][f]=Z; }
        }
        #pragma unroll
        for (int t=0;t<4;t++){
          bf16x8 a[3];
          #pragma unroll
          for (int mf=0;mf<3;mf++){
            unsigned row = rowbase + mf*16 + l15;
            a[mf] = *(const bf16x8*)(sm + FLDSX + ((row*256 + t*64 + g*16) ^ ((row&7)<<4)));
          }
          #pragma unroll
          for (int f=0;f<2;f++){
            bf16x8 bk = *(const bf16x8*)(qkvg + (((1*4+h)*4+t)*2+f)*512 + lane*8);
            bf16x8 bv = *(const bf16x8*)(qkvg + (((2*4+h)*4+t)*2+f)*512 + lane*8);
            #pragma unroll
            for (int mf=0;mf<3;mf++){
              ak[mf][f] = MFMA16(a[mf], bk, ak[mf][f]);
              av[mf][f] = MFMA16(a[mf], bv, av[mf][f]);
            }
          }
        }
        #pragma unroll
        for (int mf=0;mf<3;mf++){
          #pragma unroll
          for (int f=0;f<2;f++){
            int d = f*16 + l15;
            #pragma unroll
            for (int j=0;j<4;j++){
              int key = rowbase + mf*16 + g*4 + j;
              *(bf16*)(sm + FLDSK + ((key*64 + d*2) ^ (((key>>1)&7)<<4))) = (bf16)ak[mf][f][j];
              *(bf16*)(sm + FLDSV + ((d*768 + key*2) ^ ((d&7)<<4)))       = (bf16)av[mf][f][j];
            }
          }
        }
      }
      __syncthreads();
      const unsigned scb = FLDSS + w*1024;
      f32x4 q0=Z, q1=Z;
      #pragma unroll
      for (int t=0;t<4;t++){
        unsigned row = qb + l15;
        bf16x8 a  = *(const bf16x8*)(sm + FLDSX + ((row*256 + t*64 + g*16) ^ ((row&7)<<4)));
        bf16x8 b0 = *(const bf16x8*)(qkvg + (((0*4+h)*4+t)*2+0)*512 + lane*8);
        bf16x8 b1 = *(const bf16x8*)(qkvg + (((0*4+h)*4+t)*2+1)*512 + lane*8);
        q0 = MFMA16(a, b0, q0);
        q1 = MFMA16(a, b1, q1);
      }
      #pragma unroll
      for (int f=0;f<2;f++){
        f32x4 qq = f ? q1 : q0;
        #pragma unroll
        for (int j=0;j<4;j++){
          unsigned r = g*4 + j, cb = (f*16 + l15)*2;
          *(bf16*)(sm + scb + ((r*64 + cb) ^ (((r>>1)&7)<<4))) = (bf16)qq[j];
        }
      }
      bf16x8 aq = *(const bf16x8*)(sm + scb + ((l15*64 + g*16) ^ (((l15>>1)&7)<<4)));
      float m_[4], sum_[4];
      #pragma unroll
      for (int j=0;j<4;j++){ m_[j] = -3e38f; sum_[j] = 0.f; }
      f32x4 o0=Z, o1=Z;
      #pragma unroll
      for (int c=0;c<2;c++){
        f32x4 S[12];
        #pragma unroll
        for (int nf=0;nf<12;nf++){
          int key = c*192 + nf*16 + l15;
          bf16x8 bk = *(const bf16x8*)(sm + FLDSK + ((key*64 + g*16) ^ (((key>>1)&7)<<4)));
          S[nf] = MFMA16(aq, bk, Z);
        }
        const float* nbh = nb + (size_t)h*(NN*NN) + (size_t)(qb + g*4)*NN + c*192 + l15;
        #pragma unroll
        for (int nf=0;nf<12;nf++){
          int key = c*192 + nf*16 + l15;
          float mkb = *(const float*)(sm + FLDSM + key*4);
          #pragma unroll
          for (int j=0;j<4;j++)
            S[nf][j] += mkb + nbh[j*NN + nf*16];
        }
        float cm[4] = {-3e38f,-3e38f,-3e38f,-3e38f};
        #pragma unroll
        for (int nf=0;nf<12;nf++){
          #pragma unroll
          for (int j=0;j<4;j++) cm[j] = fmaxf(cm[j], S[nf][j]);
        }
        #pragma unroll
        for (int m=1;m<16;m<<=1){
          #pragma unroll
          for (int j=0;j<4;j++) cm[j] = fmaxf(cm[j], __shfl_xor(cm[j], m));
        }
        float sc_[4];
        #pragma unroll
        for (int j=0;j<4;j++){
          float mn = fmaxf(m_[j], cm[j]);
          sc_[j] = __expf(m_[j] - mn);
          m_[j] = mn;
        }
        float ps[4] = {0.f,0.f,0.f,0.f};
        #pragma unroll
        for (int nf=0;nf<12;nf++){
          #pragma unroll
          for (int j=0;j<4;j++){
            float pv = __expf(S[nf][j] - m_[j]);
            S[nf][j] = pv;
            ps[j] += pv;
          }
        }
        #pragma unroll
        for (int m=1;m<16;m<<=1){
          #pragma unroll
          for (int j=0;j<4;j++) ps[j] += __shfl_xor(ps[j], m);
        }
        #pragma unroll
        for (int j=0;j<4;j++){
          sum_[j] = sum_[j]*sc_[j] + ps[j];
          o0[j] *= sc_[j];
          o1[j] *= sc_[j];
        }
        #pragma unroll
        for (int t=0;t<6;t++){
          int tg = c*6 + t;
          #pragma unroll
          for (int ff=0; ff<2; ff++){
            int nf = 2*t + ff;
            #pragma unroll
            for (int j=0;j<4;j++){
              unsigned r = g*4 + j, cb = (ff*16 + l15)*2;
              *(bf16*)(sm + scb + ((r*64 + cb) ^ (((r>>1)&7)<<4))) = (bf16)S[nf][j];
            }
          }
          bf16x8 ap  = *(const bf16x8*)(sm + scb + ((l15*64 + g*16) ^ (((l15>>1)&7)<<4)));
          bf16x8 bv0 = *(const bf16x8*)(sm + FLDSV + ((l15*768      + tg*64 + g*16) ^ ((l15&7)<<4)));
          bf16x8 bv1 = *(const bf16x8*)(sm + FLDSV + (((16+l15)*768 + tg*64 + g*16) ^ ((l15&7)<<4)));
          o0 = MFMA16(ap, bv0, o0);
          o1 = MFMA16(ap, bv1, o1);
        }
      }
      float rs[4];
      #pragma unroll
      for (int j=0;j<4;j++) rs[j] = 1.f/sum_[j];
      f32x4 g0=Z, g1=Z;
      #pragma unroll
      for (int t=0;t<4;t++){
        unsigned row = qb + l15;
        bf16x8 a  = *(const bf16x8*)(sm + FLDSX + ((row*256 + t*64 + g*16) ^ ((row&7)<<4)));
        bf16x8 b0 = *(const bf16x8*)(qkvg + (((3*4+h)*4+t)*2+0)*512 + lane*8);
        bf16x8 b1 = *(const bf16x8*)(qkvg + (((3*4+h)*4+t)*2+1)*512 + lane*8);
        g0 = MFMA16(a, b0, g0);
        g1 = MFMA16(a, b1, g1);
      }
      #pragma unroll
      for (int f=0;f<2;f++){
        f32x4 ov = f ? o1 : o0, gv = f ? g1 : g0;
        int d = f*16 + l15;
        float gbv = gb[h*32 + d];
        #pragma unroll
        for (int j=0;j<4;j++){
          float gt = 1.f/(1.f + __expf(-(gv[j] + gbv)));
          float wg = ov[j]*rs[j]*gt;
          unsigned r = g*4 + j, cb = (unsigned)d*2;
          *(bf16*)(sm + scb + ((r*64 + cb) ^ (((r>>1)&7)<<4))) = (bf16)wg;
        }
      }
      bf16x8 awg = *(const bf16x8*)(sm + scb + ((l15*64 + g*16) ^ (((l15>>1)&7)<<4)));
      #pragma unroll
      for (int nf=0;nf<8;nf++){
        bf16x8 bo = *(const bf16x8*)(opk + ((h*8+nf)*64 + lane)*8);
        outa[nf] = MFMA16(awg, bo, outa[nf]);
      }
    }
    #pragma unroll
    for (int nf=0;nf<8;nf++){
      int c = nf*16 + l15;
      float obv = ob[c];
      #pragma unroll
      for (int j=0;j<4;j++){
        int qi = qb + g*4 + j;
        out[((size_t)b*NN + qi)*CC + c] = outa[nf][j] + obv;
      }
    }
  }
}

extern "C" void kernel_launch(void* const* d_in, const int* in_sizes, int n_in,
                              void* d_out, int out_size, void* d_ws, size_t ws_size,
                              hipStream_t stream)
{
  (void)in_sizes; (void)n_in; (void)out_size;
  const float* pa  = (const float*)d_in[0];
  const int*   msk = (const int*)d_in[1];
  const float* lns = (const float*)d_in[2];
  const float* lnb = (const float*)d_in[3];
  const float* fw  = (const float*)d_in[4];
  const float* qw  = (const float*)d_in[5];
  const float* kw  = (const float*)d_in[6];
  const float* vw  = (const float*)d_in[7];
  const float* gw  = (const float*)d_in[8];
  const float* gbv = (const float*)d_in[9];
  const float* ow  = (const float*)d_in[10];
  const float* ob  = (const float*)d_in[11];
  float* out = (float*)d_out;

  char* ws = (char*)d_ws;
  bf16*  xbuf  = (bf16*)(ws);
  float* nbbuf = (float*)(ws + WS_NB);
  bf16*  qkvg  = (bf16*)(ws + WS_QKVG);
  bf16*  opk   = (bf16*)(ws + WS_OP);

  pack_kernel<<<40, 256, 0, stream>>>(qw, kw, vw, gw, ow, qkvg, opk);
  ln_kernel<<<1152, 256, 0, stream>>>(pa, lns, lnb, fw, xbuf, nbbuf);

  if (ws_size >= (size_t)WS_NEED){
    bf16* kbuf = (bf16*)(ws + WS_KB);
    bf16* vbuf = (bf16*)(ws + WS_VB);
    proj_kv_kernel<<<4608, 256, 0, stream>>>(xbuf, qkvg, kbuf, vbuf);
    hipFuncSetAttribute((const void*)attn_kernel5,
                        hipFuncAttributeMaxDynamicSharedMemorySize, LDSTOT5);
    attn_kernel5<<<384, 512, LDSTOT5, stream>>>(xbuf, msk, nbbuf, qkvg, kbuf, vbuf,
                                                opk, gbv, ob, out);
  } else {
    hipFuncSetAttribute((const void*)attn_kernel_fb,
                        hipFuncAttributeMaxDynamicSharedMemorySize, FLDSTOT);
    attn_kernel_fb<<<384, 512, FLDSTOT, stream>>>(xbuf, msk, nbbuf, qkvg, opk, gbv, ob, out);
  }
}

// Round 6
// 346.518 us; speedup vs baseline: 4.8512x; 1.5354x over previous
//
#include <hip/hip_runtime.h>

typedef __bf16 bf16;
typedef __bf16 bf16x8 __attribute__((ext_vector_type(8)));
typedef float f32x4 __attribute__((ext_vector_type(4)));
typedef unsigned int u32;

#define NN 384
#define CC 128

#define MFMA16(a,b,c) __builtin_amdgcn_mfma_f32_16x16x32_bf16(a,b,c,0,0,0)

// ---------------- workspace layout (bytes) ----------------
#define WS_NB   37748736          // nb fp32 [h][q][k]      2,359,296
#define WS_QKVG 40108032          // qkvg B-frag pack       131,072
#define WS_OP   40239104          // o_w pack               32,768
#define WS_KB   40271872          // K frags bf16 [b][h][24][64][8]  37,748,736
#define WS_VB   78020608          // V^T frags bf16 [b][h][24][...]  37,748,736
#define WS_NEED 115769344

__device__ __forceinline__ void async_copy16(void* lds_dst, const void* gsrc){
  __builtin_amdgcn_global_load_lds((const __attribute__((address_space(1))) u32*)gsrc,
                                   (__attribute__((address_space(3))) u32*)lds_dst, 16, 0, 0);
}

// ---------------- K0: pre-pack weights into MFMA B-fragment order ----------------
__global__ __launch_bounds__(256) void pack_kernel(
    const float* __restrict__ qw, const float* __restrict__ kw,
    const float* __restrict__ vw, const float* __restrict__ gw,
    const float* __restrict__ ow, bf16* __restrict__ qkvg, bf16* __restrict__ op)
{
  int tid = blockIdx.x*256 + threadIdx.x;
  int lane = tid & 63, frag = tid >> 6;
  if (frag < 128) {                       // ((wm*4+h)*4+t)*2+f
    int f = frag & 1, t = (frag>>1)&3, h = (frag>>3)&3, wm = frag>>5;
    const float* W = wm==0?qw: (wm==1?kw: (wm==2?vw: gw));
    float sc = (wm==0) ? 0.17677669529663687f : 1.0f;   // q * D^-0.5 folded in
    int d = f*16 + (lane&15);
    #pragma unroll
    for (int j=0;j<8;j++){
      int c = t*32 + (lane>>4)*8 + j;
      qkvg[tid*8 + j] = (bf16)(W[c*128 + h*32 + d]*sc);
    }
  } else if (frag < 160) {                // o_w
    int fr = frag - 128, f = fr & 7, t = fr>>3;
    int c = f*16 + (lane&15);
    #pragma unroll
    for (int j=0;j<8;j++){
      int d = (lane>>4)*8 + j;
      op[(fr*64 + lane)*8 + j] = (bf16)ow[(t*32 + d)*128 + c];
    }
  }
}

// ---------------- K1: LayerNorm (fp32) -> x bf16, + nb_bias [h][q][k] ----------------
__global__ __launch_bounds__(256) void ln_kernel(
    const float* __restrict__ pa, const float* __restrict__ lns,
    const float* __restrict__ lnb, const float* __restrict__ fw,
    bf16* __restrict__ xout, float* __restrict__ nbout)
{
  int wid = (blockIdx.x*256 + threadIdx.x) >> 6;
  int lane = threadIdx.x & 63;
  int nw = (gridDim.x*256) >> 6;
  float2 sc = *(const float2*)(lns + lane*2);
  float2 bi = *(const float2*)(lnb + lane*2);
  float4 f0 = *(const float4*)(fw + lane*8);
  float4 f1 = *(const float4*)(fw + lane*8 + 4);
  for (int row = wid; row < NN*NN; row += nw){
    float2 v = *(const float2*)(pa + row*128 + lane*2);
    float s = v.x + v.y;
    float sq = v.x*v.x + v.y*v.y;
    #pragma unroll
    for (int m=1;m<64;m<<=1){ s += __shfl_xor(s,m); sq += __shfl_xor(sq,m); }
    float mu = s*(1.f/128.f);
    float rstd = rsqrtf(sq*(1.f/128.f) - mu*mu + 1e-5f);
    float x0 = (v.x-mu)*rstd*sc.x + bi.x;
    float x1 = (v.y-mu)*rstd*sc.y + bi.y;
    unsigned short h0 = __builtin_bit_cast(unsigned short, (bf16)x0);
    unsigned short h1 = __builtin_bit_cast(unsigned short, (bf16)x1);
    *(unsigned int*)((char*)xout + row*256 + lane*4) = ((unsigned int)h1<<16)|h0;
    float4 t;
    t.x = x0*f0.x + x1*f1.x;
    t.y = x0*f0.y + x1*f1.y;
    t.z = x0*f0.z + x1*f1.z;
    t.w = x0*f0.w + x1*f1.w;
    #pragma unroll
    for (int m=1;m<64;m<<=1){
      t.x += __shfl_xor(t.x,m); t.y += __shfl_xor(t.y,m);
      t.z += __shfl_xor(t.z,m); t.w += __shfl_xor(t.w,m);
    }
    float vsel = (lane==0)?t.x : (lane==1)?t.y : (lane==2)?t.z : t.w;
    if (lane < 4) nbout[(size_t)lane*(NN*NN) + row] = vsel;
  }
}

// ---------------- K2: K/V projection GEMM -> fragment-packed buffers ----------------
__global__ __launch_bounds__(256) void proj_kv_kernel(
    const bf16* __restrict__ xg, const bf16* __restrict__ qkvg,
    bf16* __restrict__ kbuf, bf16* __restrict__ vbuf)
{
  __shared__ char psm[16384];
  const int w = threadIdx.x>>6, lane = threadIdx.x&63, g = lane>>4, l15 = lane&15;
  const int W = blockIdx.x*4 + w;
  const int rt = W>>1, wm = 1 + (W&1);
  const f32x4 Z = {0.f,0.f,0.f,0.f};
  f32x4 acc[8];
  #pragma unroll
  for (int f8=0;f8<8;f8++) acc[f8] = Z;
  const bf16* xrow = xg + (size_t)(rt*16 + l15)*CC;
  #pragma unroll
  for (int t=0;t<4;t++){
    bf16x8 a = *(const bf16x8*)(xrow + t*32 + g*8);
    #pragma unroll
    for (int f8=0; f8<8; f8++){
      int h = f8>>1, fh = f8&1;
      bf16x8 bb = *(const bf16x8*)(qkvg + (((wm*4+h)*4+t)*2+fh)*512 + lane*8);
      acc[f8] = MFMA16(a, bb, acc[f8]);
    }
  }
  char* scr = psm + w*4096;
  #pragma unroll
  for (int f8=0; f8<8; f8++){
    #pragma unroll
    for (int j=0;j<4;j++){
      unsigned r = g*4+j;
      *(bf16*)(scr + ((r*256 + (f8*16+l15)*2) ^ (((r>>1)&7)<<4))) = (bf16)acc[f8][j];
    }
  }
  const int bq = rt/24, tau = rt%24;
  if (wm==1){
    #pragma unroll
    for (int h=0;h<4;h++){
      bf16x8 kf = *(const bf16x8*)(scr + ((l15*256 + h*64 + g*16) ^ (((l15>>1)&7)<<4)));
      *(bf16x8*)(kbuf + (((size_t)(bq*4+h)*24 + tau)*64 + lane)*8) = kf;
    }
  } else {
    const int k0b = (lane>>5)*8 + (lane&1)*4;
    const int dl = (lane>>1)&15;
    #pragma unroll
    for (int h=0;h<4;h++){
      #pragma unroll
      for (int nf=0;nf<2;nf++){
        unsigned short tv[4];
        #pragma unroll
        for (int j2=0;j2<4;j2++){
          int k0 = k0b + j2;
          tv[j2] = *(unsigned short*)(scr + ((k0*256 + (h*32+nf*16+dl)*2) ^ (((k0>>1)&7)<<4)));
        }
        uint2 u;
        u.x = (u32)tv[0] | ((u32)tv[1]<<16);
        u.y = (u32)tv[2] | ((u32)tv[3]<<16);
        *(uint2*)((char*)vbuf + (((size_t)(bq*4+h)*24 + (tau&~1) + nf)*1024) + (tau&1)*512 + lane*8) = u;
      }
    }
  }
}

// ---------------- K3: fused attention v6 ----------------
// Changes vs v5: waves_per_eu(2,2) -> 256-reg unified budget (kills the 128-reg
// spill that produced 250+ MB scratch traffic); double-buffered K/V LDS staging
// with prefetch-next-iteration (one barrier per (p,h)); x A-frags loaded once
// and reused for Q and gate.
#define LDSKV6 0        // 2 bufs x (K 24KiB + V 24KiB)
#define LDSM6  98304    // mask bias fp32 [384]
#define LDSS6  99840    // per-wave scratch 2 slots x 1 KiB
#define LDSTOT6 116224

__global__ __attribute__((amdgpu_flat_work_group_size(512,512), amdgpu_waves_per_eu(2,2)))
void attn_kernel6(
    const bf16* __restrict__ xg, const int* __restrict__ mask,
    const float* __restrict__ nb, const bf16* __restrict__ qkvg,
    const bf16* __restrict__ kbuf, const bf16* __restrict__ vbuf,
    const bf16* __restrict__ opk, const float* __restrict__ gb,
    const float* __restrict__ ob, float* __restrict__ out)
{
  extern __shared__ char sm[];
  const int b = blockIdx.x;
  const int tid = threadIdx.x;
  const int lane = tid & 63, w = tid >> 6;
  const int g = lane >> 4, l15 = lane & 15;
  const f32x4 Z = {0.f,0.f,0.f,0.f};

  if (tid < NN)
    *(float*)(sm + LDSM6 + tid*4) = 1e9f*((float)mask[b*NN + tid] - 1.0f);

  const int rowbase = w*48;
  const size_t kvbase = (size_t)b*4*24576;
  const unsigned scb = LDSS6 + w*2048;

  // prologue: stage h=0 into buf 0
  {
    const char* kg = (const char*)kbuf + kvbase;
    const char* vg = (const char*)vbuf + kvbase;
    #pragma unroll
    for (int i=0;i<3;i++){
      unsigned u = (i*512 + w*64)*16;
      async_copy16(sm + LDSKV6 + u,         kg + u + lane*16);
      async_copy16(sm + LDSKV6 + 24576 + u, vg + u + lane*16);
    }
  }
  int cur = 0;

  for (int p=0;p<3;p++){
    const int qb = rowbase + p*16;
    f32x4 outa[8];
    #pragma unroll
    for (int nf=0;nf<8;nf++) outa[nf] = Z;

    for (int h=0; h<4; ++h){
      // Barrier: (1) drains this wave's outstanding global_load_lds (implicit
      // vmcnt(0) before s_barrier) so buf[cur] staged last iteration is ready;
      // (2) all waves are past reading buf[cur^1] -> safe to overwrite it.
      __syncthreads();

      // prefetch next (p,h) K/V into buf[cur^1]
      {
        int nidx = p*4 + h + 1;
        if (nidx < 12){
          int hn = nidx & 3;
          const char* kg = (const char*)kbuf + kvbase + (size_t)hn*24576;
          const char* vg = (const char*)vbuf + kvbase + (size_t)hn*24576;
          char* kd = sm + LDSKV6 + (cur^1)*49152;
          #pragma unroll
          for (int i=0;i<3;i++){
            unsigned u = (i*512 + w*64)*16;
            async_copy16(kd + u,         kg + u + lane*16);
            async_copy16(kd + 24576 + u, vg + u + lane*16);
          }
        }
      }
      const char* kb = sm + LDSKV6 + cur*49152;
      const char* vb = kb + 24576;

      // ---- x A-frags (global, L2-hot), Q + gate projections together ----
      bf16x8 a[4];
      #pragma unroll
      for (int t=0;t<4;t++)
        a[t] = *(const bf16x8*)(xg + (size_t)(b*NN + qb + l15)*CC + t*32 + g*8);
      f32x4 q0=Z, q1=Z, g0=Z, g1=Z;
      #pragma unroll
      for (int t=0;t<4;t++){
        bf16x8 bq0 = *(const bf16x8*)(qkvg + (((0*4+h)*4+t)*2+0)*512 + lane*8);
        bf16x8 bq1 = *(const bf16x8*)(qkvg + (((0*4+h)*4+t)*2+1)*512 + lane*8);
        bf16x8 bg0 = *(const bf16x8*)(qkvg + (((3*4+h)*4+t)*2+0)*512 + lane*8);
        bf16x8 bg1 = *(const bf16x8*)(qkvg + (((3*4+h)*4+t)*2+1)*512 + lane*8);
        q0 = MFMA16(a[t], bq0, q0);
        q1 = MFMA16(a[t], bq1, q1);
        g0 = MFMA16(a[t], bg0, g0);
        g1 = MFMA16(a[t], bg1, g1);
      }
      // bounce Q accum -> A-frag (slot 0)
      #pragma unroll
      for (int f=0;f<2;f++){
        f32x4 qq = f ? q1 : q0;
        #pragma unroll
        for (int j=0;j<4;j++){
          unsigned r = g*4 + j, cb = (f*16 + l15)*2;
          *(bf16*)(sm + scb + ((r*64 + cb) ^ (((r>>1)&7)<<4))) = (bf16)qq[j];
        }
      }
      bf16x8 aq = *(const bf16x8*)(sm + scb + ((l15*64 + g*16) ^ (((l15>>1)&7)<<4)));

      // ---- online softmax + PV over three 128-key chunks ----
      float m_[4], sum_[4];
      #pragma unroll
      for (int j=0;j<4;j++){ m_[j] = -3e38f; sum_[j] = 0.f; }
      f32x4 o0=Z, o1=Z;

      #pragma unroll
      for (int c=0;c<3;c++){
        f32x4 S[8];
        #pragma unroll
        for (int nf=0;nf<8;nf++){
          bf16x8 bk = *(const bf16x8*)(kb + (c*8+nf)*1024 + lane*16);
          S[nf] = MFMA16(aq, bk, Z);
        }
        const float* nbh = nb + (size_t)h*(NN*NN) + (size_t)(qb + g*4)*NN + c*128 + l15;
        #pragma unroll
        for (int nf=0;nf<8;nf++){
          int key = c*128 + nf*16 + l15;
          float mkb = *(const float*)(sm + LDSM6 + key*4);
          #pragma unroll
          for (int j=0;j<4;j++)
            S[nf][j] += mkb + nbh[j*NN + nf*16];
        }
        float cm[4] = {-3e38f,-3e38f,-3e38f,-3e38f};
        #pragma unroll
        for (int nf=0;nf<8;nf++){
          #pragma unroll
          for (int j=0;j<4;j++) cm[j] = fmaxf(cm[j], S[nf][j]);
        }
        #pragma unroll
        for (int m=1;m<16;m<<=1){
          #pragma unroll
          for (int j=0;j<4;j++) cm[j] = fmaxf(cm[j], __shfl_xor(cm[j], m));
        }
        float sc_[4];
        #pragma unroll
        for (int j=0;j<4;j++){
          float mn = fmaxf(m_[j], cm[j]);
          sc_[j] = __expf(m_[j] - mn);
          m_[j] = mn;
        }
        float ps[4] = {0.f,0.f,0.f,0.f};
        #pragma unroll
        for (int nf=0;nf<8;nf++){
          #pragma unroll
          for (int j=0;j<4;j++){
            float pv = __expf(S[nf][j] - m_[j]);
            S[nf][j] = pv;
            ps[j] += pv;
          }
        }
        #pragma unroll
        for (int m=1;m<16;m<<=1){
          #pragma unroll
          for (int j=0;j<4;j++) ps[j] += __shfl_xor(ps[j], m);
        }
        #pragma unroll
        for (int j=0;j<4;j++){
          sum_[j] = sum_[j]*sc_[j] + ps[j];
          o0[j] *= sc_[j];
          o1[j] *= sc_[j];
        }
        // PV: 4 key-chunks of 32 (double-slot bounce)
        #pragma unroll
        for (int t=0;t<4;t++){
          int tg = c*4 + t;
          unsigned slot = scb + (t&1)*1024;
          #pragma unroll
          for (int ff=0; ff<2; ff++){
            int nf = 2*t + ff;
            #pragma unroll
            for (int j=0;j<4;j++){
              unsigned r = g*4 + j, cb2 = (ff*16 + l15)*2;
              *(bf16*)(sm + slot + ((r*64 + cb2) ^ (((r>>1)&7)<<4))) = (bf16)S[nf][j];
            }
          }
          bf16x8 ap  = *(const bf16x8*)(sm + slot + ((l15*64 + g*16) ^ (((l15>>1)&7)<<4)));
          bf16x8 bv0 = *(const bf16x8*)(vb + (tg*2+0)*1024 + lane*16);
          bf16x8 bv1 = *(const bf16x8*)(vb + (tg*2+1)*1024 + lane*16);
          o0 = MFMA16(ap, bv0, o0);
          o1 = MFMA16(ap, bv1, o1);
        }
      } // c

      float rs[4];
      #pragma unroll
      for (int j=0;j<4;j++) rs[j] = 1.f/sum_[j];

      // ---- wg = (O/s)*sigmoid(G+gb); bounce (slot 0); out-projection ----
      #pragma unroll
      for (int f=0;f<2;f++){
        f32x4 ov = f ? o1 : o0, gv = f ? g1 : g0;
        int d = f*16 + l15;
        float gbv = gb[h*32 + d];
        #pragma unroll
        for (int j=0;j<4;j++){
          float gt = 1.f/(1.f + __expf(-(gv[j] + gbv)));
          float wg = ov[j]*rs[j]*gt;
          unsigned r = g*4 + j, cb2 = (unsigned)d*2;
          *(bf16*)(sm + scb + ((r*64 + cb2) ^ (((r>>1)&7)<<4))) = (bf16)wg;
        }
      }
      bf16x8 awg = *(const bf16x8*)(sm + scb + ((l15*64 + g*16) ^ (((l15>>1)&7)<<4)));
      #pragma unroll
      for (int nf=0;nf<8;nf++){
        bf16x8 bo = *(const bf16x8*)(opk + ((h*8+nf)*64 + lane)*8);
        outa[nf] = MFMA16(awg, bo, outa[nf]);
      }
      cur ^= 1;
    } // h

    #pragma unroll
    for (int nf=0;nf<8;nf++){
      int c = nf*16 + l15;
      float obv = ob[c];
      #pragma unroll
      for (int j=0;j<4;j++){
        int qi = qb + g*4 + j;
        out[((size_t)b*NN + qi)*CC + c] = outa[nf][j] + obv;
      }
    }
  } // p
}

// ---------------- Fallback: r4 attention (used if ws too small) ----------------
#define FLDSX 0
#define FLDSK 98304
#define FLDSV 122880
#define FLDSM 147456
#define FLDSS 148992
#define FLDSTOT 157184

__global__ __attribute__((amdgpu_flat_work_group_size(512,512), amdgpu_waves_per_eu(2,2)))
void attn_kernel_fb(
    const bf16* __restrict__ xg, const int* __restrict__ mask,
    const float* __restrict__ nb, const bf16* __restrict__ qkvg,
    const bf16* __restrict__ opk, const float* __restrict__ gb,
    const float* __restrict__ ob, float* __restrict__ out)
{
  extern __shared__ char sm[];
  const int b = blockIdx.x;
  const int tid = threadIdx.x;
  const int lane = tid & 63, w = tid >> 6;
  const int g = lane >> 4, l15 = lane & 15;
  const f32x4 Z = {0.f,0.f,0.f,0.f};
  {
    const uint4* src = (const uint4*)(xg + (size_t)b*NN*CC);
    #pragma unroll
    for (int it=0; it<12; ++it){
      unsigned u = it*512 + tid;
      unsigned row = u >> 4;
      unsigned dst = (u*16) ^ ((row&7)<<4);
      *(uint4*)(sm + FLDSX + dst) = src[u];
    }
    if (tid < NN)
      *(float*)(sm + FLDSM + tid*4) = 1e9f*((float)mask[b*NN + tid] - 1.0f);
  }
  const int rowbase = w*48;
  for (int p=0;p<3;p++){
    const int qb = rowbase + p*16;
    f32x4 outa[8];
    #pragma unroll
    for (int nf=0;nf<8;nf++) outa[nf] = Z;
    for (int h=0; h<4; ++h){
      __syncthreads();
      {
        f32x4 ak[3][2], av[3][2];
        #pragma unroll
        for (int mf=0;mf<3;mf++){
          #pragma unroll
          for (int f=0;f<2;f++){ ak[mf][f]=Z; av[mf][f]=Z; }
        }
        #pragma unroll
        for (int t=0;t<4;t++){
          bf16x8 a[3];
          #pragma unroll
          for (int mf=0;mf<3;mf++){
            unsigned row = rowbase + mf*16 + l15;
            a[mf] = *(const bf16x8*)(sm + FLDSX + ((row*256 + t*64 + g*16) ^ ((row&7)<<4)));
          }
          #pragma unroll
          for (int f=0;f<2;f++){
            bf16x8 bk = *(const bf16x8*)(qkvg + (((1*4+h)*4+t)*2+f)*512 + lane*8);
            bf16x8 bv = *(const bf16x8*)(qkvg + (((2*4+h)*4+t)*2+f)*512 + lane*8);
            #pragma unroll
            for (int mf=0;mf<3;mf++){
              ak[mf][f] = MFMA16(a[mf], bk, ak[mf][f]);
              av[mf][f] = MFMA16(a[mf], bv, av[mf][f]);
            }
          }
        }
        #pragma unroll
        for (int mf=0;mf<3;mf++){
          #pragma unroll
          for (int f=0;f<2;f++){
            int d = f*16 + l15;
            #pragma unroll
            for (int j=0;j<4;j++){
              int key = rowbase + mf*16 + g*4 + j;
              *(bf16*)(sm + FLDSK + ((key*64 + d*2) ^ (((key>>1)&7)<<4))) = (bf16)ak[mf][f][j];
              *(bf16*)(sm + FLDSV + ((d*768 + key*2) ^ ((d&7)<<4)))       = (bf16)av[mf][f][j];
            }
          }
        }
      }
      __syncthreads();
      const unsigned scb = FLDSS + w*1024;
      f32x4 q0=Z, q1=Z;
      #pragma unroll
      for (int t=0;t<4;t++){
        unsigned row = qb + l15;
        bf16x8 a  = *(const bf16x8*)(sm + FLDSX + ((row*256 + t*64 + g*16) ^ ((row&7)<<4)));
        bf16x8 b0 = *(const bf16x8*)(qkvg + (((0*4+h)*4+t)*2+0)*512 + lane*8);
        bf16x8 b1 = *(const bf16x8*)(qkvg + (((0*4+h)*4+t)*2+1)*512 + lane*8);
        q0 = MFMA16(a, b0, q0);
        q1 = MFMA16(a, b1, q1);
      }
      #pragma unroll
      for (int f=0;f<2;f++){
        f32x4 qq = f ? q1 : q0;
        #pragma unroll
        for (int j=0;j<4;j++){
          unsigned r = g*4 + j, cb = (f*16 + l15)*2;
          *(bf16*)(sm + scb + ((r*64 + cb) ^ (((r>>1)&7)<<4))) = (bf16)qq[j];
        }
      }
      bf16x8 aq = *(const bf16x8*)(sm + scb + ((l15*64 + g*16) ^ (((l15>>1)&7)<<4)));
      float m_[4], sum_[4];
      #pragma unroll
      for (int j=0;j<4;j++){ m_[j] = -3e38f; sum_[j] = 0.f; }
      f32x4 o0=Z, o1=Z;
      #pragma unroll
      for (int c=0;c<2;c++){
        f32x4 S[12];
        #pragma unroll
        for (int nf=0;nf<12;nf++){
          int key = c*192 + nf*16 + l15;
          bf16x8 bk = *(const bf16x8*)(sm + FLDSK + ((key*64 + g*16) ^ (((key>>1)&7)<<4)));
          S[nf] = MFMA16(aq, bk, Z);
        }
        const float* nbh = nb + (size_t)h*(NN*NN) + (size_t)(qb + g*4)*NN + c*192 + l15;
        #pragma unroll
        for (int nf=0;nf<12;nf++){
          int key = c*192 + nf*16 + l15;
          float mkb = *(const float*)(sm + FLDSM + key*4);
          #pragma unroll
          for (int j=0;j<4;j++)
            S[nf][j] += mkb + nbh[j*NN + nf*16];
        }
        float cm[4] = {-3e38f,-3e38f,-3e38f,-3e38f};
        #pragma unroll
        for (int nf=0;nf<12;nf++){
          #pragma unroll
          for (int j=0;j<4;j++) cm[j] = fmaxf(cm[j], S[nf][j]);
        }
        #pragma unroll
        for (int m=1;m<16;m<<=1){
          #pragma unroll
          for (int j=0;j<4;j++) cm[j] = fmaxf(cm[j], __shfl_xor(cm[j], m));
        }
        float sc_[4];
        #pragma unroll
        for (int j=0;j<4;j++){
          float mn = fmaxf(m_[j], cm[j]);
          sc_[j] = __expf(m_[j] - mn);
          m_[j] = mn;
        }
        float ps[4] = {0.f,0.f,0.f,0.f};
        #pragma unroll
        for (int nf=0;nf<12;nf++){
          #pragma unroll
          for (int j=0;j<4;j++){
            float pv = __expf(S[nf][j] - m_[j]);
            S[nf][j] = pv;
            ps[j] += pv;
          }
        }
        #pragma unroll
        for (int m=1;m<16;m<<=1){
          #pragma unroll
          for (int j=0;j<4;j++) ps[j] += __shfl_xor(ps[j], m);
        }
        #pragma unroll
        for (int j=0;j<4;j++){
          sum_[j] = sum_[j]*sc_[j] + ps[j];
          o0[j] *= sc_[j];
          o1[j] *= sc_[j];
        }
        #pragma unroll
        for (int t=0;t<6;t++){
          int tg = c*6 + t;
          #pragma unroll
          for (int ff=0; ff<2; ff++){
            int nf = 2*t + ff;
            #pragma unroll
            for (int j=0;j<4;j++){
              unsigned r = g*4 + j, cb = (ff*16 + l15)*2;
              *(bf16*)(sm + scb + ((r*64 + cb) ^ (((r>>1)&7)<<4))) = (bf16)S[nf][j];
            }
          }
          bf16x8 ap  = *(const bf16x8*)(sm + scb + ((l15*64 + g*16) ^ (((l15>>1)&7)<<4)));
          bf16x8 bv0 = *(const bf16x8*)(sm + FLDSV + ((l15*768      + tg*64 + g*16) ^ ((l15&7)<<4)));
          bf16x8 bv1 = *(const bf16x8*)(sm + FLDSV + (((16+l15)*768 + tg*64 + g*16) ^ ((l15&7)<<4)));
          o0 = MFMA16(ap, bv0, o0);
          o1 = MFMA16(ap, bv1, o1);
        }
      }
      float rs[4];
      #pragma unroll
      for (int j=0;j<4;j++) rs[j] = 1.f/sum_[j];
      f32x4 g0=Z, g1=Z;
      #pragma unroll
      for (int t=0;t<4;t++){
        unsigned row = qb + l15;
        bf16x8 a  = *(const bf16x8*)(sm + FLDSX + ((row*256 + t*64 + g*16) ^ ((row&7)<<4)));
        bf16x8 b0 = *(const bf16x8*)(qkvg + (((3*4+h)*4+t)*2+0)*512 + lane*8);
        bf16x8 b1 = *(const bf16x8*)(qkvg + (((3*4+h)*4+t)*2+1)*512 + lane*8);
        g0 = MFMA16(a, b0, g0);
        g1 = MFMA16(a, b1, g1);
      }
      #pragma unroll
      for (int f=0;f<2;f++){
        f32x4 ov = f ? o1 : o0, gv = f ? g1 : g0;
        int d = f*16 + l15;
        float gbv = gb[h*32 + d];
        #pragma unroll
        for (int j=0;j<4;j++){
          float gt = 1.f/(1.f + __expf(-(gv[j] + gbv)));
          float wg = ov[j]*rs[j]*gt;
          unsigned r = g*4 + j, cb = (unsigned)d*2;
          *(bf16*)(sm + scb + ((r*64 + cb) ^ (((r>>1)&7)<<4))) = (bf16)wg;
        }
      }
      bf16x8 awg = *(const bf16x8*)(sm + scb + ((l15*64 + g*16) ^ (((l15>>1)&7)<<4)));
      #pragma unroll
      for (int nf=0;nf<8;nf++){
        bf16x8 bo = *(const bf16x8*)(opk + ((h*8+nf)*64 + lane)*8);
        outa[nf] = MFMA16(awg, bo, outa[nf]);
      }
    }
    #pragma unroll
    for (int nf=0;nf<8;nf++){
      int c = nf*16 + l15;
      float obv = ob[c];
      #pragma unroll
      for (int j=0;j<4;j++){
        int qi = qb + g*4 + j;
        out[((size_t)b*NN + qi)*CC + c] = outa[nf][j] + obv;
      }
    }
  }
}

extern "C" void kernel_launch(void* const* d_in, const int* in_sizes, int n_in,
                              void* d_out, int out_size, void* d_ws, size_t ws_size,
                              hipStream_t stream)
{
  (void)in_sizes; (void)n_in; (void)out_size;
  const float* pa  = (const float*)d_in[0];
  const int*   msk = (const int*)d_in[1];
  const float* lns = (const float*)d_in[2];
  const float* lnb = (const float*)d_in[3];
  const float* fw  = (const float*)d_in[4];
  const float* qw  = (const float*)d_in[5];
  const float* kw  = (const float*)d_in[6];
  const float* vw  = (const float*)d_in[7];
  const float* gw  = (const float*)d_in[8];
  const float* gbv = (const float*)d_in[9];
  const float* ow  = (const float*)d_in[10];
  const float* ob  = (const float*)d_in[11];
  float* out = (float*)d_out;

  char* ws = (char*)d_ws;
  bf16*  xbuf  = (bf16*)(ws);
  float* nbbuf = (float*)(ws + WS_NB);
  bf16*  qkvg  = (bf16*)(ws + WS_QKVG);
  bf16*  opk   = (bf16*)(ws + WS_OP);

  pack_kernel<<<40, 256, 0, stream>>>(qw, kw, vw, gw, ow, qkvg, opk);
  ln_kernel<<<1152, 256, 0, stream>>>(pa, lns, lnb, fw, xbuf, nbbuf);

  if (ws_size >= (size_t)WS_NEED){
    bf16* kbuf = (bf16*)(ws + WS_KB);
    bf16* vbuf = (bf16*)(ws + WS_VB);
    proj_kv_kernel<<<4608, 256, 0, stream>>>(xbuf, qkvg, kbuf, vbuf);
    hipFuncSetAttribute((const void*)attn_kernel6,
                        hipFuncAttributeMaxDynamicSharedMemorySize, LDSTOT6);
    attn_kernel6<<<384, 512, LDSTOT6, stream>>>(xbuf, msk, nbbuf, qkvg, kbuf, vbuf,
                                                opk, gbv, ob, out);
  } else {
    hipFuncSetAttribute((const void*)attn_kernel_fb,
                        hipFuncAttributeMaxDynamicSharedMemorySize, FLDSTOT);
    attn_kernel_fb<<<384, 512, FLDSTOT, stream>>>(xbuf, msk, nbbuf, qkvg, opk, gbv, ob, out);
  }
}

// Round 7
// 337.390 us; speedup vs baseline: 4.9824x; 1.0271x over previous
//
#include <hip/hip_runtime.h>

typedef __bf16 bf16;
typedef __bf16 bf16x8 __attribute__((ext_vector_type(8)));
typedef __bf16 bf16x4v __attribute__((ext_vector_type(4)));
typedef short s16x4 __attribute__((ext_vector_type(4)));
typedef float f32x4 __attribute__((ext_vector_type(4)));
typedef unsigned int u32;
typedef unsigned long long u64;

#define NN 384
#define CC 128

#define MFMA16(a,b,c) __builtin_amdgcn_mfma_f32_16x16x32_bf16(a,b,c,0,0,0)

// 16x16x16 bf16 MFMA: prefer new-style builtin if present, else gfx90a _1k (short4 args)
#if __has_builtin(__builtin_amdgcn_mfma_f32_16x16x16_bf16)
typedef bf16x4v pvab_t;
static __device__ __forceinline__ f32x4 PVMFMA(pvab_t A, bf16x4v B, f32x4 C){
  return __builtin_amdgcn_mfma_f32_16x16x16_bf16(A, B, C, 0,0,0);
}
static __device__ __forceinline__ pvab_t mk_pvab(u32 w0, u32 w1){
  return __builtin_bit_cast(pvab_t, (u64)w0 | ((u64)w1<<32));
}
#else
typedef s16x4 pvab_t;
static __device__ __forceinline__ f32x4 PVMFMA(pvab_t A, bf16x4v B, f32x4 C){
  return __builtin_amdgcn_mfma_f32_16x16x16bf16_1k(A, __builtin_bit_cast(s16x4, B), C, 0,0,0);
}
static __device__ __forceinline__ pvab_t mk_pvab(u32 w0, u32 w1){
  return __builtin_bit_cast(pvab_t, (u64)w0 | ((u64)w1<<32));
}
#endif

static __device__ __forceinline__ u32 bpack(float a, float b){
  unsigned short x = __builtin_bit_cast(unsigned short, (bf16)a);
  unsigned short y = __builtin_bit_cast(unsigned short, (bf16)b);
  return (u32)x | ((u32)y<<16);
}

// ---------------- workspace layout (bytes) ----------------
#define WS_NB   37748736          // nb fp32 [h][q][k]      2,359,296
#define WS_QKVG 40108032          // qkvg B-frag pack       131,072
#define WS_OP   40239104          // o_w pack               32,768
#define WS_KB   40271872          // K A-frags bf16 [b][h][24][1KiB]  37,748,736
#define WS_VB   78020608          // V B16-frags bf16 [b][h][24][1KiB] 37,748,736
#define WS_NEED 115769344

__device__ __forceinline__ void async_copy16(void* lds_dst, const void* gsrc){
  __builtin_amdgcn_global_load_lds((const __attribute__((address_space(1))) u32*)gsrc,
                                   (__attribute__((address_space(3))) u32*)lds_dst, 16, 0, 0);
}

// ---------------- K0: pre-pack weights into MFMA B-fragment order ----------------
__global__ __launch_bounds__(256) void pack_kernel(
    const float* __restrict__ qw, const float* __restrict__ kw,
    const float* __restrict__ vw, const float* __restrict__ gw,
    const float* __restrict__ ow, bf16* __restrict__ qkvg, bf16* __restrict__ op)
{
  int tid = blockIdx.x*256 + threadIdx.x;
  int lane = tid & 63, frag = tid >> 6;
  if (frag < 128) {                       // ((wm*4+h)*4+t)*2+f
    int f = frag & 1, t = (frag>>1)&3, h = (frag>>3)&3, wm = frag>>5;
    const float* W = wm==0?qw: (wm==1?kw: (wm==2?vw: gw));
    float sc = (wm==0) ? 0.17677669529663687f : 1.0f;   // q * D^-0.5 folded in
    int d = f*16 + (lane&15);
    #pragma unroll
    for (int j=0;j<8;j++){
      int c = t*32 + (lane>>4)*8 + j;
      qkvg[tid*8 + j] = (bf16)(W[c*128 + h*32 + d]*sc);
    }
  } else if (frag < 160) {                // o_w
    int fr = frag - 128, f = fr & 7, t = fr>>3;
    int c = f*16 + (lane&15);
    #pragma unroll
    for (int j=0;j<8;j++){
      int d = (lane>>4)*8 + j;
      op[(fr*64 + lane)*8 + j] = (bf16)ow[(t*32 + d)*128 + c];
    }
  }
}

// ---------------- K1: LayerNorm (fp32) -> x bf16, + nb_bias [h][q][k] ----------------
__global__ __launch_bounds__(256) void ln_kernel(
    const float* __restrict__ pa, const float* __restrict__ lns,
    const float* __restrict__ lnb, const float* __restrict__ fw,
    bf16* __restrict__ xout, float* __restrict__ nbout)
{
  int wid = (blockIdx.x*256 + threadIdx.x) >> 6;
  int lane = threadIdx.x & 63;
  int nw = (gridDim.x*256) >> 6;
  float2 sc = *(const float2*)(lns + lane*2);
  float2 bi = *(const float2*)(lnb + lane*2);
  float4 f0 = *(const float4*)(fw + lane*8);
  float4 f1 = *(const float4*)(fw + lane*8 + 4);
  for (int row = wid; row < NN*NN; row += nw){
    float2 v = *(const float2*)(pa + row*128 + lane*2);
    float s = v.x + v.y;
    float sq = v.x*v.x + v.y*v.y;
    #pragma unroll
    for (int m=1;m<64;m<<=1){ s += __shfl_xor(s,m); sq += __shfl_xor(sq,m); }
    float mu = s*(1.f/128.f);
    float rstd = rsqrtf(sq*(1.f/128.f) - mu*mu + 1e-5f);
    float x0 = (v.x-mu)*rstd*sc.x + bi.x;
    float x1 = (v.y-mu)*rstd*sc.y + bi.y;
    unsigned short h0 = __builtin_bit_cast(unsigned short, (bf16)x0);
    unsigned short h1 = __builtin_bit_cast(unsigned short, (bf16)x1);
    *(unsigned int*)((char*)xout + row*256 + lane*4) = ((unsigned int)h1<<16)|h0;
    float4 t;
    t.x = x0*f0.x + x1*f1.x;
    t.y = x0*f0.y + x1*f1.y;
    t.z = x0*f0.z + x1*f1.z;
    t.w = x0*f0.w + x1*f1.w;
    #pragma unroll
    for (int m=1;m<64;m<<=1){
      t.x += __shfl_xor(t.x,m); t.y += __shfl_xor(t.y,m);
      t.z += __shfl_xor(t.z,m); t.w += __shfl_xor(t.w,m);
    }
    float vsel = (lane==0)?t.x : (lane==1)?t.y : (lane==2)?t.z : t.w;
    if (lane < 4) nbout[(size_t)lane*(NN*NN) + row] = vsel;
  }
}

// ---------------- K2: K/V projection GEMM -> fragment-packed buffers ----------------
// K per (b,h,tau): A-frag32 for S^T: lane holds K[key=l15][d=g*8+j] (16B/lane, 1KiB/frag)
// V per (b,h,tau): B-frag16 pair:    lane holds V[key=tau*16+4g+j][d=fh*16+l15] j=0..3,
//                  stored as uint4 {fh0:j01,j23, fh1:j01,j23} = raw C/D accum (lane-local!)
__global__ __launch_bounds__(256) void proj_kv_kernel(
    const bf16* __restrict__ xg, const bf16* __restrict__ qkvg,
    bf16* __restrict__ kbuf, bf16* __restrict__ vbuf)
{
  __shared__ char psm[16384];
  const int w = threadIdx.x>>6, lane = threadIdx.x&63, g = (lane>>4)&3, l15 = lane&15;
  const int W = blockIdx.x*4 + w;
  const int rt = W>>1, wm = 1 + (W&1);
  const f32x4 Z = {0.f,0.f,0.f,0.f};
  f32x4 acc[8];
  #pragma unroll
  for (int f8=0;f8<8;f8++) acc[f8] = Z;
  const bf16* xrow = xg + (size_t)(rt*16 + l15)*CC;
  #pragma unroll
  for (int t=0;t<4;t++){
    bf16x8 a = *(const bf16x8*)(xrow + t*32 + g*8);
    #pragma unroll
    for (int f8=0; f8<8; f8++){
      int h = f8>>1, fh = f8&1;
      bf16x8 bb = *(const bf16x8*)(qkvg + (((wm*4+h)*4+t)*2+fh)*512 + lane*8);
      acc[f8] = MFMA16(a, bb, acc[f8]);
    }
  }
  const int bq = rt/24, tau = rt%24;
  if (wm==1){
    // K: transpose C/D -> A-frag via LDS bounce
    char* scr = psm + w*4096;
    #pragma unroll
    for (int f8=0; f8<8; f8++){
      #pragma unroll
      for (int j=0;j<4;j++){
        unsigned r = g*4+j;
        *(bf16*)(scr + ((r*256 + (f8*16+l15)*2) ^ (((r>>1)&7)<<4))) = (bf16)acc[f8][j];
      }
    }
    #pragma unroll
    for (int h=0;h<4;h++){
      bf16x8 kf = *(const bf16x8*)(scr + ((l15*256 + h*64 + g*16) ^ (((l15>>1)&7)<<4)));
      *(bf16x8*)(kbuf + (((size_t)(bq*4+h)*24 + tau)*64 + lane)*8) = kf;
    }
  } else {
    // V: C/D accum IS the B-frag16 layout -> direct lane-local store
    #pragma unroll
    for (int h=0;h<4;h++){
      f32x4 a0 = acc[h*2+0], a1 = acc[h*2+1];
      uint4 st4;
      st4.x = bpack(a0[0], a0[1]);
      st4.y = bpack(a0[2], a0[3]);
      st4.z = bpack(a1[0], a1[1]);
      st4.w = bpack(a1[2], a1[3]);
      *(uint4*)((char*)vbuf + ((size_t)(bq*4+h)*24 + tau)*1024 + lane*16) = st4;
    }
  }
}

// ---------------- K3: fused attention v7 (swapped-S^T, register PV) ----------------
#define LDSKV7 0        // 2 bufs x (K 24KiB + V 24KiB)
#define LDSM7  98304    // mask bias fp32 [384]
#define LDSS7  99840    // per-wave scratch 1 KiB
#define LDSTOT7 108032

__global__ __attribute__((amdgpu_flat_work_group_size(512,512), amdgpu_waves_per_eu(2,2)))
void attn_kernel7(
    const bf16* __restrict__ xg, const int* __restrict__ mask,
    const float* __restrict__ nb, const bf16* __restrict__ qkvg,
    const bf16* __restrict__ kbuf, const bf16* __restrict__ vbuf,
    const bf16* __restrict__ opk, const float* __restrict__ gb,
    const float* __restrict__ ob, float* __restrict__ out)
{
  extern __shared__ char sm[];
  const int b = blockIdx.x;
  const int tid = threadIdx.x;
  const int lane = tid & 63, w = tid >> 6;
  const int g = (lane >> 4)&3, l15 = lane & 15;
  const f32x4 Z = {0.f,0.f,0.f,0.f};

  if (tid < NN)
    *(float*)(sm + LDSM7 + tid*4) = 1e9f*((float)mask[b*NN + tid] - 1.0f);

  const int rowbase = w*48;
  const size_t kvbase = (size_t)b*4*24576;
  const unsigned scb = LDSS7 + w*1024;

  // prologue: stage h=0 into buf 0
  {
    const char* kg = (const char*)kbuf + kvbase;
    const char* vg = (const char*)vbuf + kvbase;
    #pragma unroll
    for (int i=0;i<3;i++){
      unsigned u = (i*512 + w*64)*16;
      async_copy16(sm + LDSKV7 + u,         kg + u + lane*16);
      async_copy16(sm + LDSKV7 + 24576 + u, vg + u + lane*16);
    }
  }
  int cur = 0;

  for (int p=0;p<3;p++){
    const int qb = rowbase + p*16;
    f32x4 outa[8];
    #pragma unroll
    for (int nf=0;nf<8;nf++) outa[nf] = Z;

    // x A-frags: h-invariant, load once per p
    bf16x8 a4[4];
    #pragma unroll
    for (int t=0;t<4;t++)
      a4[t] = *(const bf16x8*)(xg + (size_t)(b*NN + qb + l15)*CC + t*32 + g*8);

    for (int h=0; h<4; ++h){
      __syncthreads();   // buf[cur] staged (vmcnt drain) + all waves done with buf[cur^1]

      // prefetch next (p,h) K/V into buf[cur^1]
      {
        int nidx = p*4 + h + 1;
        if (nidx < 12){
          int hn = nidx & 3;
          const char* kg = (const char*)kbuf + kvbase + (size_t)hn*24576;
          const char* vg = (const char*)vbuf + kvbase + (size_t)hn*24576;
          char* kd = sm + LDSKV7 + (cur^1)*49152;
          #pragma unroll
          for (int i=0;i<3;i++){
            unsigned u = (i*512 + w*64)*16;
            async_copy16(kd + u,         kg + u + lane*16);
            async_copy16(kd + 24576 + u, vg + u + lane*16);
          }
        }
      }
      const char* kb = sm + LDSKV7 + cur*49152;
      const char* vb = kb + 24576;

      // ---- Q + gate projections ----
      f32x4 q0=Z, q1=Z, g0=Z, g1=Z;
      #pragma unroll
      for (int t=0;t<4;t++){
        bf16x8 bq0 = *(const bf16x8*)(qkvg + (((0*4+h)*4+t)*2+0)*512 + lane*8);
        bf16x8 bq1 = *(const bf16x8*)(qkvg + (((0*4+h)*4+t)*2+1)*512 + lane*8);
        bf16x8 bg0 = *(const bf16x8*)(qkvg + (((3*4+h)*4+t)*2+0)*512 + lane*8);
        bf16x8 bg1 = *(const bf16x8*)(qkvg + (((3*4+h)*4+t)*2+1)*512 + lane*8);
        q0 = MFMA16(a4[t], bq0, q0);
        q1 = MFMA16(a4[t], bq1, q1);
        g0 = MFMA16(a4[t], bg0, g0);
        g1 = MFMA16(a4[t], bg1, g1);
      }
      // bounce Q accum -> B-frag (lane holds Q[q=l15][d=g*8+j])
      #pragma unroll
      for (int f=0;f<2;f++){
        f32x4 qq = f ? q1 : q0;
        #pragma unroll
        for (int j=0;j<4;j++){
          unsigned r = g*4 + j, cb = (f*16 + l15)*2;
          *(bf16*)(sm + scb + ((r*64 + cb) ^ (((r>>1)&7)<<4))) = (bf16)qq[j];
        }
      }
      bf16x8 aq = *(const bf16x8*)(sm + scb + ((l15*64 + g*16) ^ (((l15>>1)&7)<<4)));

      // ---- online softmax (per-lane q=l15) + register PV, three 128-key chunks ----
      float m_ = -3e38f, sum_ = 0.f;
      f32x4 o0=Z, o1=Z;
      const float* nbq = nb + (size_t)h*(NN*NN) + (size_t)(qb + l15)*NN;

      #pragma unroll
      for (int c=0;c<3;c++){
        // S^T = K · Q^T : lane holds S^T[key=c*128+nf*16+4g+j][q=l15]
        f32x4 st[8];
        #pragma unroll
        for (int nf=0;nf<8;nf++){
          bf16x8 ka = *(const bf16x8*)(kb + (c*8+nf)*1024 + lane*16);
          st[nf] = MFMA16(ka, aq, Z);
        }
        // biases: mask (LDS float4, broadcast) + nb (global float4)
        #pragma unroll
        for (int nf=0;nf<8;nf++){
          float4 mk  = *(const float4*)(sm + LDSM7 + (c*128 + nf*16 + g*4)*4);
          float4 nbv = *(const float4*)(nbq + c*128 + nf*16 + g*4);
          st[nf][0] += mk.x + nbv.x;
          st[nf][1] += mk.y + nbv.y;
          st[nf][2] += mk.z + nbv.z;
          st[nf][3] += mk.w + nbv.w;
        }
        // chunk max: in-lane over 32 + 2 shuffles across g
        float cm = st[0][0];
        #pragma unroll
        for (int nf=0;nf<8;nf++){
          #pragma unroll
          for (int j=0;j<4;j++) cm = fmaxf(cm, st[nf][j]);
        }
        cm = fmaxf(cm, __shfl_xor(cm, 16));
        cm = fmaxf(cm, __shfl_xor(cm, 32));
        float mn = fmaxf(m_, cm);
        float sc = __expf(m_ - mn);
        m_ = mn;
        float ps = 0.f;
        #pragma unroll
        for (int nf=0;nf<8;nf++){
          #pragma unroll
          for (int j=0;j<4;j++){
            float pv = __expf(st[nf][j] - m_);
            st[nf][j] = pv;
            ps += pv;
          }
        }
        ps += __shfl_xor(ps, 16);
        ps += __shfl_xor(ps, 32);
        sum_ = sum_*sc + ps;
        // rescale O (C/D rows q=4g+j need sc from lane l15=4g+j)
        #pragma unroll
        for (int j=0;j<4;j++){
          float scd = __shfl(sc, (lane & 0x30) + g*4 + j);
          o0[j] *= scd;
          o1[j] *= scd;
        }
        // PV: P already in A-frag16 layout -> pack to bf16, MFMA directly
        #pragma unroll
        for (int nf=0;nf<8;nf++){
          pvab_t pa = mk_pvab(bpack(st[nf][0], st[nf][1]), bpack(st[nf][2], st[nf][3]));
          bf16x8 vv = *(const bf16x8*)(vb + (c*8+nf)*1024 + lane*16);
          bf16x4v vlo = {vv[0],vv[1],vv[2],vv[3]};
          bf16x4v vhi = {vv[4],vv[5],vv[6],vv[7]};
          o0 = PVMFMA(pa, vlo, o0);
          o1 = PVMFMA(pa, vhi, o1);
        }
      } // c

      // 1/sum redistributed to C/D rows
      float rsl = 1.f/sum_;
      float rcd[4];
      #pragma unroll
      for (int j=0;j<4;j++)
        rcd[j] = __shfl(rsl, (lane & 0x30) + g*4 + j);

      // ---- wg = (O/s)*sigmoid(G+gb); bounce; out-projection ----
      #pragma unroll
      for (int f=0;f<2;f++){
        f32x4 ov = f ? o1 : o0, gv = f ? g1 : g0;
        int d = f*16 + l15;
        float gbv = gb[h*32 + d];
        #pragma unroll
        for (int j=0;j<4;j++){
          float gt = 1.f/(1.f + __expf(-(gv[j] + gbv)));
          float wg = ov[j]*rcd[j]*gt;
          unsigned r = g*4 + j, cb2 = (unsigned)d*2;
          *(bf16*)(sm + scb + ((r*64 + cb2) ^ (((r>>1)&7)<<4))) = (bf16)wg;
        }
      }
      bf16x8 awg = *(const bf16x8*)(sm + scb + ((l15*64 + g*16) ^ (((l15>>1)&7)<<4)));
      #pragma unroll
      for (int nf=0;nf<8;nf++){
        bf16x8 bo = *(const bf16x8*)(opk + ((h*8+nf)*64 + lane)*8);
        outa[nf] = MFMA16(awg, bo, outa[nf]);
      }
      cur ^= 1;
    } // h

    #pragma unroll
    for (int nf=0;nf<8;nf++){
      int c = nf*16 + l15;
      float obv = ob[c];
      #pragma unroll
      for (int j=0;j<4;j++){
        int qi = qb + g*4 + j;
        out[((size_t)b*NN + qi)*CC + c] = outa[nf][j] + obv;
      }
    }
  } // p
}

// ---------------- Fallback: r4 attention (used if ws too small) ----------------
#define FLDSX 0
#define FLDSK 98304
#define FLDSV 122880
#define FLDSM 147456
#define FLDSS 148992
#define FLDSTOT 157184

__global__ __attribute__((amdgpu_flat_work_group_size(512,512), amdgpu_waves_per_eu(2,2)))
void attn_kernel_fb(
    const bf16* __restrict__ xg, const int* __restrict__ mask,
    const float* __restrict__ nb, const bf16* __restrict__ qkvg,
    const bf16* __restrict__ opk, const float* __restrict__ gb,
    const float* __restrict__ ob, float* __restrict__ out)
{
  extern __shared__ char sm[];
  const int b = blockIdx.x;
  const int tid = threadIdx.x;
  const int lane = tid & 63, w = tid >> 6;
  const int g = lane >> 4, l15 = lane & 15;
  const f32x4 Z = {0.f,0.f,0.f,0.f};
  {
    const uint4* src = (const uint4*)(xg + (size_t)b*NN*CC);
    #pragma unroll
    for (int it=0; it<12; ++it){
      unsigned u = it*512 + tid;
      unsigned row = u >> 4;
      unsigned dst = (u*16) ^ ((row&7)<<4);
      *(uint4*)(sm + FLDSX + dst) = src[u];
    }
    if (tid < NN)
      *(float*)(sm + FLDSM + tid*4) = 1e9f*((float)mask[b*NN + tid] - 1.0f);
  }
  const int rowbase = w*48;
  for (int p=0;p<3;p++){
    const int qb = rowbase + p*16;
    f32x4 outa[8];
    #pragma unroll
    for (int nf=0;nf<8;nf++) outa[nf] = Z;
    for (int h=0; h<4; ++h){
      __syncthreads();
      {
        f32x4 ak[3][2], av[3][2];
        #pragma unroll
        for (int mf=0;mf<3;mf++){
          #pragma unroll
          for (int f=0;f<2;f++){ ak[mf][f]=Z; av[mf][f]=Z; }
        }
        #pragma unroll
        for (int t=0;t<4;t++){
          bf16x8 a[3];
          #pragma unroll
          for (int mf=0;mf<3;mf++){
            unsigned row = rowbase + mf*16 + l15;
            a[mf] = *(const bf16x8*)(sm + FLDSX + ((row*256 + t*64 + g*16) ^ ((row&7)<<4)));
          }
          #pragma unroll
          for (int f=0;f<2;f++){
            bf16x8 bk = *(const bf16x8*)(qkvg + (((1*4+h)*4+t)*2+f)*512 + lane*8);
            bf16x8 bv = *(const bf16x8*)(qkvg + (((2*4+h)*4+t)*2+f)*512 + lane*8);
            #pragma unroll
            for (int mf=0;mf<3;mf++){
              ak[mf][f] = MFMA16(a[mf], bk, ak[mf][f]);
              av[mf][f] = MFMA16(a[mf], bv, av[mf][f]);
            }
          }
        }
        #pragma unroll
        for (int mf=0;mf<3;mf++){
          #pragma unroll
          for (int f=0;f<2;f++){
            int d = f*16 + l15;
            #pragma unroll
            for (int j=0;j<4;j++){
              int key = rowbase + mf*16 + g*4 + j;
              *(bf16*)(sm + FLDSK + ((key*64 + d*2) ^ (((key>>1)&7)<<4))) = (bf16)ak[mf][f][j];
              *(bf16*)(sm + FLDSV + ((d*768 + key*2) ^ ((d&7)<<4)))       = (bf16)av[mf][f][j];
            }
          }
        }
      }
      __syncthreads();
      const unsigned scb = FLDSS + w*1024;
      f32x4 q0=Z, q1=Z;
      #pragma unroll
      for (int t=0;t<4;t++){
        unsigned row = qb + l15;
        bf16x8 a  = *(const bf16x8*)(sm + FLDSX + ((row*256 + t*64 + g*16) ^ ((row&7)<<4)));
        bf16x8 b0 = *(const bf16x8*)(qkvg + (((0*4+h)*4+t)*2+0)*512 + lane*8);
        bf16x8 b1 = *(const bf16x8*)(qkvg + (((0*4+h)*4+t)*2+1)*512 + lane*8);
        q0 = MFMA16(a, b0, q0);
        q1 = MFMA16(a, b1, q1);
      }
      #pragma unroll
      for (int f=0;f<2;f++){
        f32x4 qq = f ? q1 : q0;
        #pragma unroll
        for (int j=0;j<4;j++){
          unsigned r = g*4 + j, cb = (f*16 + l15)*2;
          *(bf16*)(sm + scb + ((r*64 + cb) ^ (((r>>1)&7)<<4))) = (bf16)qq[j];
        }
      }
      bf16x8 aq = *(const bf16x8*)(sm + scb + ((l15*64 + g*16) ^ (((l15>>1)&7)<<4)));
      float m_[4], sum_[4];
      #pragma unroll
      for (int j=0;j<4;j++){ m_[j] = -3e38f; sum_[j] = 0.f; }
      f32x4 o0=Z, o1=Z;
      #pragma unroll
      for (int c=0;c<2;c++){
        f32x4 S[12];
        #pragma unroll
        for (int nf=0;nf<12;nf++){
          int key = c*192 + nf*16 + l15;
          bf16x8 bk = *(const bf16x8*)(sm + FLDSK + ((key*64 + g*16) ^ (((key>>1)&7)<<4)));
          S[nf] = MFMA16(aq, bk, Z);
        }
        const float* nbh = nb + (size_t)h*(NN*NN) + (size_t)(qb + g*4)*NN + c*192 + l15;
        #pragma unroll
        for (int nf=0;nf<12;nf++){
          int key = c*192 + nf*16 + l15;
          float mkb = *(const float*)(sm + FLDSM + key*4);
          #pragma unroll
          for (int j=0;j<4;j++)
            S[nf][j] += mkb + nbh[j*NN + nf*16];
        }
        float cm[4] = {-3e38f,-3e38f,-3e38f,-3e38f};
        #pragma unroll
        for (int nf=0;nf<12;nf++){
          #pragma unroll
          for (int j=0;j<4;j++) cm[j] = fmaxf(cm[j], S[nf][j]);
        }
        #pragma unroll
        for (int m=1;m<16;m<<=1){
          #pragma unroll
          for (int j=0;j<4;j++) cm[j] = fmaxf(cm[j], __shfl_xor(cm[j], m));
        }
        float sc_[4];
        #pragma unroll
        for (int j=0;j<4;j++){
          float mn = fmaxf(m_[j], cm[j]);
          sc_[j] = __expf(m_[j] - mn);
          m_[j] = mn;
        }
        float ps[4] = {0.f,0.f,0.f,0.f};
        #pragma unroll
        for (int nf=0;nf<12;nf++){
          #pragma unroll
          for (int j=0;j<4;j++){
            float pv = __expf(S[nf][j] - m_[j]);
            S[nf][j] = pv;
            ps[j] += pv;
          }
        }
        #pragma unroll
        for (int m=1;m<16;m<<=1){
          #pragma unroll
          for (int j=0;j<4;j++) ps[j] += __shfl_xor(ps[j], m);
        }
        #pragma unroll
        for (int j=0;j<4;j++){
          sum_[j] = sum_[j]*sc_[j] + ps[j];
          o0[j] *= sc_[j];
          o1[j] *= sc_[j];
        }
        #pragma unroll
        for (int t=0;t<6;t++){
          int tg = c*6 + t;
          #pragma unroll
          for (int ff=0; ff<2; ff++){
            int nf = 2*t + ff;
            #pragma unroll
            for (int j=0;j<4;j++){
              unsigned r = g*4 + j, cb = (ff*16 + l15)*2;
              *(bf16*)(sm + scb + ((r*64 + cb) ^ (((r>>1)&7)<<4))) = (bf16)S[nf][j];
            }
          }
          bf16x8 ap  = *(const bf16x8*)(sm + scb + ((l15*64 + g*16) ^ (((l15>>1)&7)<<4)));
          bf16x8 bv0 = *(const bf16x8*)(sm + FLDSV + ((l15*768      + tg*64 + g*16) ^ ((l15&7)<<4)));
          bf16x8 bv1 = *(const bf16x8*)(sm + FLDSV + (((16+l15)*768 + tg*64 + g*16) ^ ((l15&7)<<4)));
          o0 = MFMA16(ap, bv0, o0);
          o1 = MFMA16(ap, bv1, o1);
        }
      }
      float rs[4];
      #pragma unroll
      for (int j=0;j<4;j++) rs[j] = 1.f/sum_[j];
      f32x4 g0=Z, g1=Z;
      #pragma unroll
      for (int t=0;t<4;t++){
        unsigned row = qb + l15;
        bf16x8 a  = *(const bf16x8*)(sm + FLDSX + ((row*256 + t*64 + g*16) ^ ((row&7)<<4)));
        bf16x8 b0 = *(const bf16x8*)(qkvg + (((3*4+h)*4+t)*2+0)*512 + lane*8);
        bf16x8 b1 = *(const bf16x8*)(qkvg + (((3*4+h)*4+t)*2+1)*512 + lane*8);
        g0 = MFMA16(a, b0, g0);
        g1 = MFMA16(a, b1, g1);
      }
      #pragma unroll
      for (int f=0;f<2;f++){
        f32x4 ov = f ? o1 : o0, gv = f ? g1 : g0;
        int d = f*16 + l15;
        float gbv = gb[h*32 + d];
        #pragma unroll
        for (int j=0;j<4;j++){
          float gt = 1.f/(1.f + __expf(-(gv[j] + gbv)));
          float wg = ov[j]*rs[j]*gt;
          unsigned r = g*4 + j, cb = (unsigned)d*2;
          *(bf16*)(sm + scb + ((r*64 + cb) ^ (((r>>1)&7)<<4))) = (bf16)wg;
        }
      }
      bf16x8 awg = *(const bf16x8*)(sm + scb + ((l15*64 + g*16) ^ (((l15>>1)&7)<<4)));
      #pragma unroll
      for (int nf=0;nf<8;nf++){
        bf16x8 bo = *(const bf16x8*)(opk + ((h*8+nf)*64 + lane)*8);
        outa[nf] = MFMA16(awg, bo, outa[nf]);
      }
    }
    #pragma unroll
    for (int nf=0;nf<8;nf++){
      int c = nf*16 + l15;
      float obv = ob[c];
      #pragma unroll
      for (int j=0;j<4;j++){
        int qi = qb + g*4 + j;
        out[((size_t)b*NN + qi)*CC + c] = outa[nf][j] + obv;
      }
    }
  }
}

extern "C" void kernel_launch(void* const* d_in, const int* in_sizes, int n_in,
                              void* d_out, int out_size, void* d_ws, size_t ws_size,
                              hipStream_t stream)
{
  (void)in_sizes; (void)n_in; (void)out_size;
  const float* pa  = (const float*)d_in[0];
  const int*   msk = (const int*)d_in[1];
  const float* lns = (const float*)d_in[2];
  const float* lnb = (const float*)d_in[3];
  const float* fw  = (const float*)d_in[4];
  const float* qw  = (const float*)d_in[5];
  const float* kw  = (const float*)d_in[6];
  const float* vw  = (const float*)d_in[7];
  const float* gw  = (const float*)d_in[8];
  const float* gbv = (const float*)d_in[9];
  const float* ow  = (const float*)d_in[10];
  const float* ob  = (const float*)d_in[11];
  float* out = (float*)d_out;

  char* ws = (char*)d_ws;
  bf16*  xbuf  = (bf16*)(ws);
  float* nbbuf = (float*)(ws + WS_NB);
  bf16*  qkvg  = (bf16*)(ws + WS_QKVG);
  bf16*  opk   = (bf16*)(ws + WS_OP);

  pack_kernel<<<40, 256, 0, stream>>>(qw, kw, vw, gw, ow, qkvg, opk);
  ln_kernel<<<1152, 256, 0, stream>>>(pa, lns, lnb, fw, xbuf, nbbuf);

  if (ws_size >= (size_t)WS_NEED){
    bf16* kbuf = (bf16*)(ws + WS_KB);
    bf16* vbuf = (bf16*)(ws + WS_VB);
    proj_kv_kernel<<<4608, 256, 0, stream>>>(xbuf, qkvg, kbuf, vbuf);
    hipFuncSetAttribute((const void*)attn_kernel7,
                        hipFuncAttributeMaxDynamicSharedMemorySize, LDSTOT7);
    attn_kernel7<<<384, 512, LDSTOT7, stream>>>(xbuf, msk, nbbuf, qkvg, kbuf, vbuf,
                                                opk, gbv, ob, out);
  } else {
    hipFuncSetAttribute((const void*)attn_kernel_fb,
                        hipFuncAttributeMaxDynamicSharedMemorySize, FLDSTOT);
    attn_kernel_fb<<<384, 512, FLDSTOT, stream>>>(xbuf, msk, nbbuf, qkvg, opk, gbv, ob, out);
  }
}